// Round 7
// baseline (1321.370 us; speedup 1.0000x reference)
//
#include <hip/hip_runtime.h>
#include <stdint.h>

typedef _Float16 f16_t;
typedef _Float16 f16x8 __attribute__((ext_vector_type(8)));
typedef _Float16 f16x4 __attribute__((ext_vector_type(4)));
typedef float f32x4 __attribute__((ext_vector_type(4)));

#define GLL16(g, l)                                                                   \
  __builtin_amdgcn_global_load_lds((const __attribute__((address_space(1))) uint32_t*)(g), \
                                   (__attribute__((address_space(3))) uint32_t*)(l),  \
                                   16, 0, 0)

// ---------------------------------------------------------------------------
// Plain 128x128 GEMM tile mainloop (BK=64, 256 threads, single-buffered).
// Proven plateau core; used by the vt role. Do not touch.
// ---------------------------------------------------------------------------
__device__ __forceinline__ void gemm_tile(const f16_t* __restrict__ A, long lda,
                                          const f16_t* __restrict__ B, long ldb,
                                          int kTiles, f16_t* lA, f16_t* lB,
                                          f32x4 acc[4][4])
{
  const int tid  = threadIdx.x;
  const int wave = tid >> 6;
  const int lane = tid & 63;

  const f16_t* pA[4];
  const f16_t* pB[4];
  f16_t* lAb[4];
  f16_t* lBb[4];
#pragma unroll
  for (int i = 0; i < 4; ++i) {
    int c  = i * 256 + wave * 64 + lane;
    int m  = c & 127;
    int kq = c >> 7;
    pA[i]  = A + (long)m * lda + kq * 8;
    pB[i]  = B + (long)m * ldb + kq * 8;
    int cb = i * 256 + wave * 64;
    lAb[i] = lA + (long)cb * 8;
    lBb[i] = lB + (long)cb * 8;
  }
  const int lm = lane & 15;
  const int q  = lane >> 4;
  const int wi = (wave >> 1) * 64;
  const int wj = (wave & 1) * 64;

  for (int kt = 0; kt < kTiles; ++kt) {
    long ko = (long)kt * 64;
#pragma unroll
    for (int i = 0; i < 4; ++i) GLL16(pA[i] + ko, lAb[i]);
#pragma unroll
    for (int i = 0; i < 4; ++i) GLL16(pB[i] + ko, lBb[i]);
    __syncthreads();
#pragma unroll
    for (int s = 0; s < 2; ++s) {
      f16x8 af[4], bfr[4];
#pragma unroll
      for (int i = 0; i < 4; ++i)
        af[i] = *(const f16x8*)(lA + (((s * 4 + q) * 128) + wi + i * 16 + lm) * 8);
#pragma unroll
      for (int j = 0; j < 4; ++j)
        bfr[j] = *(const f16x8*)(lB + (((s * 4 + q) * 128) + wj + j * 16 + lm) * 8);
#pragma unroll
      for (int i = 0; i < 4; ++i)
#pragma unroll
        for (int j = 0; j < 4; ++j)
          acc[i][j] = __builtin_amdgcn_mfma_f32_16x16x32_f16(af[i], bfr[j], acc[i][j], 0, 0, 0);
    }
    __syncthreads();
  }
}

// ---------------------------------------------------------------------------
// Fused hi/lo 3-product mainloop (BK=32, single-buffered, proven):
// C += Ah*Bh^T + Al*Bh^T + Ah*Bl^T. 4 LDS bufs x 8 KB = 32 KB.
// (used by the tw branch of k_tw_vt)
// ---------------------------------------------------------------------------
__device__ __forceinline__ void gemm_tile3(const f16_t* __restrict__ Ah,
                                           const f16_t* __restrict__ Al, long lda,
                                           const f16_t* __restrict__ Bh,
                                           const f16_t* __restrict__ Bl, long ldb,
                                           int kTiles,
                                           f16_t* lAh, f16_t* lAl,
                                           f16_t* lBh, f16_t* lBl,
                                           f32x4 acc[4][4])
{
  const int tid  = threadIdx.x;
  const int wave = tid >> 6;
  const int lane = tid & 63;

  const f16_t* pAh[2]; const f16_t* pAl[2];
  const f16_t* pBh[2]; const f16_t* pBl[2];
  f16_t* dAh[2]; f16_t* dAl[2]; f16_t* dBh[2]; f16_t* dBl[2];
#pragma unroll
  for (int i = 0; i < 2; ++i) {
    int c  = i * 256 + wave * 64 + lane;   // chunk 0..511
    int m  = c & 127;
    int kq = c >> 7;                       // 0..3 (BK=32)
    long aoff = (long)m * lda + kq * 8;
    long boff = (long)m * ldb + kq * 8;
    pAh[i] = Ah + aoff;  pAl[i] = Al + aoff;
    pBh[i] = Bh + boff;  pBl[i] = Bl + boff;
    int cb = i * 256 + wave * 64;
    dAh[i] = lAh + (long)cb * 8;  dAl[i] = lAl + (long)cb * 8;
    dBh[i] = lBh + (long)cb * 8;  dBl[i] = lBl + (long)cb * 8;
  }
  const int lm = lane & 15;
  const int q  = lane >> 4;
  const int wi = (wave >> 1) * 64;
  const int wj = (wave & 1) * 64;

  for (int kt = 0; kt < kTiles; ++kt) {
    long ko = (long)kt * 32;
#pragma unroll
    for (int i = 0; i < 2; ++i) GLL16(pAh[i] + ko, dAh[i]);
#pragma unroll
    for (int i = 0; i < 2; ++i) GLL16(pAl[i] + ko, dAl[i]);
#pragma unroll
    for (int i = 0; i < 2; ++i) GLL16(pBh[i] + ko, dBh[i]);
#pragma unroll
    for (int i = 0; i < 2; ++i) GLL16(pBl[i] + ko, dBl[i]);
    __syncthreads();
    {
      f16x8 ah[4], al[4], bh[4], bl[4];
#pragma unroll
      for (int i = 0; i < 4; ++i)
        ah[i] = *(const f16x8*)(lAh + (q * 128 + wi + i * 16 + lm) * 8);
#pragma unroll
      for (int j = 0; j < 4; ++j)
        bh[j] = *(const f16x8*)(lBh + (q * 128 + wj + j * 16 + lm) * 8);
#pragma unroll
      for (int i = 0; i < 4; ++i)
#pragma unroll
        for (int j = 0; j < 4; ++j)
          acc[i][j] = __builtin_amdgcn_mfma_f32_16x16x32_f16(ah[i], bh[j], acc[i][j], 0, 0, 0);
#pragma unroll
      for (int i = 0; i < 4; ++i)
        al[i] = *(const f16x8*)(lAl + (q * 128 + wi + i * 16 + lm) * 8);
#pragma unroll
      for (int i = 0; i < 4; ++i)
#pragma unroll
        for (int j = 0; j < 4; ++j)
          acc[i][j] = __builtin_amdgcn_mfma_f32_16x16x32_f16(al[i], bh[j], acc[i][j], 0, 0, 0);
#pragma unroll
      for (int j = 0; j < 4; ++j)
        bl[j] = *(const f16x8*)(lBl + (q * 128 + wj + j * 16 + lm) * 8);
#pragma unroll
      for (int i = 0; i < 4; ++i)
#pragma unroll
        for (int j = 0; j < 4; ++j)
          acc[i][j] = __builtin_amdgcn_mfma_f32_16x16x32_f16(ah[i], bl[j], acc[i][j], 0, 0, 0);
    }
    __syncthreads();
  }
}

#define EPI_COORDS                              \
  const int tid  = threadIdx.x;                 \
  const int wave = tid >> 6;                    \
  const int lane = tid & 63;                    \
  const int lm   = lane & 15;                   \
  const int q    = lane >> 4;                   \
  const int wi   = (wave >> 1) * 64;            \
  const int wj   = (wave & 1) * 64;

#define ZERO_ACC(acc)                                            \
  _Pragma("unroll") for (int i = 0; i < 4; ++i)                  \
  _Pragma("unroll") for (int j = 0; j < 4; ++j)                  \
    acc[i][j] = (f32x4){0.f, 0.f, 0.f, 0.f};

// ---------------------------------------------------------------------------
// SHARED 4-phase hi/lo 3-product mainloop (r1/r4-proven best: 209 us).
// 256x128 tile, 512 threads, BK=32, triple-buffered (3 x 48 KB), counted
// vmcnt(6). Templated for ablation: STGE = issue global_load_lds,
// CMPU = do ds_read + MFMA. Real path is <1,1> (code-identical to r4).
// <0,0> = sync-skeleton-only probe (barriers + lgkm drains + vmcnt waits).
// ---------------------------------------------------------------------------

#define SC8_MFMA_QUAD(i0, j0)                                                   \
  __builtin_amdgcn_s_setprio(1);                                                \
  _Pragma("unroll") for (int ii = 0; ii < 2; ++ii)                              \
  _Pragma("unroll") for (int jj = 0; jj < 2; ++jj) {                            \
    acc[(i0)+ii][(j0)+jj] = __builtin_amdgcn_mfma_f32_16x16x32_f16(             \
        ah[(i0)+ii], bh[(j0)+jj], acc[(i0)+ii][(j0)+jj], 0, 0, 0);              \
    acc[(i0)+ii][(j0)+jj] = __builtin_amdgcn_mfma_f32_16x16x32_f16(             \
        al[(i0)+ii], bh[(j0)+jj], acc[(i0)+ii][(j0)+jj], 0, 0, 0);              \
    acc[(i0)+ii][(j0)+jj] = __builtin_amdgcn_mfma_f32_16x16x32_f16(             \
        ah[(i0)+ii], bl[(j0)+jj], acc[(i0)+ii][(j0)+jj], 0, 0, 0);              \
  }                                                                             \
  __builtin_amdgcn_s_setprio(0);

#define SC8_RD_A(lb, i)                                                \
  ah[i] = *(const f16x8*)((lb) + raA + (i) * 128);                     \
  al[i] = *(const f16x8*)((lb) + 8192 + raA + (i) * 128);
#define SC8_RD_B(lb, j)                                                \
  bh[j] = *(const f16x8*)((lb) + 16384 + rbB + (j) * 128);             \
  bl[j] = *(const f16x8*)((lb) + 20480 + rbB + (j) * 128);

#define SC8_BAR_LGKM                                                   \
  __builtin_amdgcn_s_barrier();                                        \
  asm volatile("s_waitcnt lgkmcnt(0)" ::: "memory");

#define SC8_STAGE_TILE(nb, T)                                    \
  {                                                              \
    long ko = (long)(T) * 32;                                    \
    GLL16(pAh0 + ko, (nb) + dA0);                                \
    GLL16(pAh1 + ko, (nb) + dA1);                                \
    GLL16(pAl0 + ko, (nb) + 8192 + dA0);                         \
    GLL16(pAl1 + ko, (nb) + 8192 + dA1);                         \
    GLL16(pBh + ko, (nb) + 16384 + dB);                          \
    GLL16(pBl + ko, (nb) + 20480 + dB);                          \
  }

// 4-phase tile body. CMPU branch = r4-exact. Non-compute branch keeps the
// identical barrier/wait skeleton with no LDS reads / MFMA.
#define SC8_TILE(LB, NB, T, ST)                                                 \
  {                                                                             \
    const f16_t* lb = (LB);                                                     \
    f16_t* nb = (NB);                                                           \
    const long ko = (long)((T) + 2) * 32;                                       \
    (void)lb; (void)nb; (void)ko;                                               \
    if (CMPU) {                                                                 \
      f16x8 ah[4], al[4], bh[4], bl[4];                                         \
      SC8_RD_A(lb, 0); SC8_RD_A(lb, 1); SC8_RD_B(lb, 0); SC8_RD_B(lb, 1);       \
      if (STGE && (ST)) { GLL16(pAh0 + ko, nb + dA0); GLL16(pAh1 + ko, nb + dA1); } \
      SC8_BAR_LGKM;                                                             \
      SC8_MFMA_QUAD(0, 0);                                                      \
      __builtin_amdgcn_s_barrier();                                             \
      SC8_RD_B(lb, 2); SC8_RD_B(lb, 3);                                         \
      if (STGE && (ST)) { GLL16(pAl0 + ko, nb + 8192 + dA0); GLL16(pAl1 + ko, nb + 8192 + dA1); } \
      SC8_BAR_LGKM;                                                             \
      SC8_MFMA_QUAD(0, 2);                                                      \
      __builtin_amdgcn_s_barrier();                                             \
      SC8_RD_A(lb, 2); SC8_RD_A(lb, 3);                                         \
      if (STGE && (ST)) GLL16(pBh + ko, nb + 16384 + dB);                       \
      SC8_BAR_LGKM;                                                             \
      SC8_MFMA_QUAD(2, 2);                                                      \
      __builtin_amdgcn_s_barrier();                                             \
      if (STGE && (ST)) GLL16(pBl + ko, nb + 20480 + dB);                       \
      SC8_BAR_LGKM;                                                             \
      SC8_MFMA_QUAD(2, 0);                                                      \
    } else {                                                                    \
      if (STGE && (ST)) { GLL16(pAh0 + ko, nb + dA0); GLL16(pAh1 + ko, nb + dA1); } \
      SC8_BAR_LGKM;                                                             \
      __builtin_amdgcn_s_barrier();                                             \
      if (STGE && (ST)) { GLL16(pAl0 + ko, nb + 8192 + dA0); GLL16(pAl1 + ko, nb + 8192 + dA1); } \
      SC8_BAR_LGKM;                                                             \
      __builtin_amdgcn_s_barrier();                                             \
      if (STGE && (ST)) GLL16(pBh + ko, nb + 16384 + dB);                       \
      SC8_BAR_LGKM;                                                             \
      __builtin_amdgcn_s_barrier();                                             \
      if (STGE && (ST)) GLL16(pBl + ko, nb + 20480 + dB);                       \
      SC8_BAR_LGKM;                                                             \
    }                                                                           \
  }

#define SC8_WAIT6_BAR                                                  \
  asm volatile("s_waitcnt vmcnt(6)" ::: "memory");                     \
  __builtin_amdgcn_s_barrier();
#define SC8_WAIT0_BAR                                                  \
  asm volatile("s_waitcnt vmcnt(0)" ::: "memory");                     \
  __builtin_amdgcn_s_barrier();

template <int STGE, int CMPU>
__device__ __forceinline__ void mainloop8_3(const f16_t* __restrict__ Ah,
                                            const f16_t* __restrict__ Al, long lda,
                                            const f16_t* __restrict__ Bh,
                                            const f16_t* __restrict__ Bl, long ldb,
                                            f16_t* lds, f32x4 acc[4][4])
{
  f16_t* bu0 = lds;
  f16_t* bu1 = lds + 24576;
  f16_t* bu2 = lds + 49152;

  const int tid  = threadIdx.x;
  const int wave = tid >> 6;
  const int lane = tid & 63;
  const int lm   = lane & 15;
  const int q    = lane >> 4;
  const int wm   = wave >> 1;   // 0..3  (M)
  const int wn   = wave & 1;    // 0..1  (N)

  const int tA_m = tid & 255, tA_k = tid >> 8;
  const f16_t* pAh0 = Ah + (long)tA_m * lda + tA_k * 8;
  const f16_t* pAh1 = pAh0 + 16;
  const f16_t* pAl0 = Al + (long)tA_m * lda + tA_k * 8;
  const f16_t* pAl1 = pAl0 + 16;
  const int tB_m = tid & 127, tB_k = tid >> 7;
  const f16_t* pBh = Bh + (long)tB_m * ldb + tB_k * 8;
  const f16_t* pBl = Bl + (long)tB_m * ldb + tB_k * 8;
  const int dA0 = wave * 512;
  const int dA1 = 4096 + wave * 512;
  const int dB  = wave * 512;

  const int raA = (q * 256 + wm * 64 + lm) * 8;
  const int rbB = (q * 128 + wn * 64 + lm) * 8;
  (void)raA; (void)rbB;

  if (STGE) {
    SC8_STAGE_TILE(bu0, 0);
    SC8_STAGE_TILE(bu1, 1);
  }
  SC8_WAIT6_BAR;

  for (int it = 0; it < 7; ++it) {
    int t0 = it * 3;
    SC8_TILE(bu0, bu2, t0, 1);     SC8_WAIT6_BAR;
    SC8_TILE(bu1, bu0, t0 + 1, 1); SC8_WAIT6_BAR;
    SC8_TILE(bu2, bu1, t0 + 2, 1); SC8_WAIT6_BAR;
  }
  SC8_TILE(bu0, bu2, 21, 1); SC8_WAIT6_BAR;
  SC8_TILE(bu1, bu0, 22, 0); SC8_WAIT0_BAR;
  SC8_TILE(bu2, bu1, 23, 0);
}

// ---- convert fp32 -> f16 hi/lo split, elementwise (vector x4)
__global__ __launch_bounds__(256) void k_cvt_split(const float* __restrict__ src,
                                                   f16_t* __restrict__ hi,
                                                   f16_t* __restrict__ lo)
{
  long i = ((long)blockIdx.x * 256 + threadIdx.x) * 4;
  float4 v = *(const float4*)(src + i);
  f16_t h0 = (f16_t)v.x, h1 = (f16_t)v.y, h2 = (f16_t)v.z, h3 = (f16_t)v.w;
  f16x4 hv = {h0, h1, h2, h3};
  f16x4 lv = {(f16_t)(v.x - (float)h0), (f16_t)(v.y - (float)h1),
              (f16_t)(v.z - (float)h2), (f16_t)(v.w - (float)h3)};
  *(f16x4*)(hi + i) = hv;
  *(f16x4*)(lo + i) = lv;
}

// ---- merged transposes: z<3 -> W branch z (768x768, hi+lo); z==3 -> params
__global__ __launch_bounds__(256) void k_transpose_all(const float* __restrict__ w0,
                                                       const float* __restrict__ w1,
                                                       const float* __restrict__ w2,
                                                       const float* __restrict__ params,
                                                       f16_t* __restrict__ Wh,
                                                       f16_t* __restrict__ Wl,
                                                       f16_t* __restrict__ paramsT)
{
  __shared__ float t[32][33];
  const int z = blockIdx.z;
  const float* src;
  f16_t* hi;
  f16_t* lo;
  int R, C;
  if (z < 3) {
    if (blockIdx.y >= 24) return;
    src = (z == 0) ? w0 : ((z == 1) ? w1 : w2);
    hi  = Wh + (long)z * 768 * 768;
    lo  = Wl + (long)z * 768 * 768;
    R = 768; C = 768;
  } else {
    src = params; hi = paramsT; lo = nullptr;
    R = 2304; C = 768;
  }
  int x = blockIdx.x * 32 + threadIdx.x;
  int y = blockIdx.y * 32 + threadIdx.y;
#pragma unroll
  for (int j = 0; j < 32; j += 8)
    t[threadIdx.y + j][threadIdx.x] = src[(long)(y + j) * C + x];
  __syncthreads();
  int x2 = blockIdx.y * 32 + threadIdx.x;
  int y2 = blockIdx.x * 32 + threadIdx.y;
#pragma unroll
  for (int j = 0; j < 32; j += 8) {
    float v  = t[threadIdx.x][threadIdx.y + j];
    long idx = (long)(y2 + j) * R + x2;
    f16_t h  = (f16_t)v;
    hi[idx] = h;
    if (lo) lo[idx] = (f16_t)(v - (float)h);
  }
}

// ---- merged tw + vt dispatch (r1/r4 proven config). z < g: tw slot z.
//      z >= g: vt block (Vt[br][b] = (node_b @ P_br)^T), linear id decode.
__global__ __launch_bounds__(256, 4) void k_tw_vt(const f16_t* __restrict__ nh,
                                                  const f16_t* __restrict__ nl,
                                                  const f16_t* __restrict__ Wh,
                                                  const f16_t* __restrict__ Wl,
                                                  const f16_t* __restrict__ paramsT,
                                                  f16_t* __restrict__ Thi,
                                                  f16_t* __restrict__ Tlo,
                                                  f16_t* __restrict__ Vt,
                                                  int br_base, int g)
{
  __shared__ __align__(16) f16_t lds[16384];   // 32 KB, shared by both roles
  if ((int)blockIdx.z < g) {
    f32x4 acc[4][4];
    ZERO_ACC(acc);
    const int slot = blockIdx.z;
    const long br  = br_base + slot;
    long aofs = (long)blockIdx.x * 128 * 768;
    long bofs = br * 768 * 768 + (long)blockIdx.y * 128 * 768;
    gemm_tile3(nh + aofs, nl + aofs, 768, Wh + bofs, Wl + bofs, 768, 24,
               lds, lds + 4096, lds + 8192, lds + 12288, acc);
    EPI_COORDS;
    long out0 = (long)slot * 8192 * 768;
    long row0 = (long)blockIdx.x * 128;
    long col0 = (long)blockIdx.y * 128;
#pragma unroll
    for (int i = 0; i < 4; ++i)
#pragma unroll
      for (int j = 0; j < 4; ++j)
#pragma unroll
        for (int r = 0; r < 4; ++r) {
          long row = row0 + wi + i * 16 + q * 4 + r;
          long col = col0 + wj + j * 16 + lm;
          float v  = acc[i][j][r];
          f16_t h  = (f16_t)v;
          Thi[out0 + row * 768 + col] = h;
          Tlo[out0 + row * 768 + col] = (f16_t)(v - (float)h);
        }
  } else {
    int id   = blockIdx.x + 64 * (blockIdx.y + 6 * (blockIdx.z - g));  // 0..1151
    int vx   = id % 6;
    int rest = id / 6;
    int vy   = rest & 7;
    int vz   = rest >> 3;        // 0..23
    int b    = vz & 7;
    int br   = vz >> 3;
    f32x4 acc[4][4];
    ZERO_ACC(acc);
    const f16_t* A = paramsT + (long)vx * 128 * 2304 + (long)br * 768;
    const f16_t* B = nh + ((long)b * 1024 + (long)vy * 128) * 768;
    gemm_tile(A, 2304, B, 768, 12, lds, lds + 8192, acc);
    EPI_COORDS;
    f16_t* C = Vt + ((long)(br * 8 + b) * 768) * 1024;
    long row0 = (long)vx * 128;
    long col0 = (long)vy * 128;
#pragma unroll
    for (int i = 0; i < 4; ++i)
#pragma unroll
      for (int j = 0; j < 4; ++j)
#pragma unroll
        for (int r = 0; r < 4; ++r) {
          long row = row0 + wi + i * 16 + q * 4 + r;
          long col = col0 + wj + j * 16 + lm;
          C[row * 1024 + col] = (f16_t)acc[i][j][r];
        }
  }
}

// ---------------------------------------------------------------------------
// Templated scores kernel. <1,1> = real (r4-exact). Probes: <1,0> stage-only,
// <0,1> compute-only, <0,0> skeleton-only. slot is clamped %3 so over-size
// probe grids stay inside the 3-slot workspace (identity for real launches).
// Probe S-writes are scratch, fully overwritten by the real pipeline in-stream.
// ---------------------------------------------------------------------------
template <int STGE, int CMPU>
__global__ __launch_bounds__(512, 2) void k_scores_t(const f16_t* __restrict__ Thi,
                                                     const f16_t* __restrict__ Tlo,
                                                     const f16_t* __restrict__ nh,
                                                     const f16_t* __restrict__ nl,
                                                     const int* __restrict__ adj0,
                                                     const int* __restrict__ adj1,
                                                     const int* __restrict__ adj2,
                                                     float* __restrict__ S, int br_base)
{
  __shared__ __align__(16) f16_t lds[3 * 24576];   // 144 KB

  const int tid  = threadIdx.x;
  const int wave = tid >> 6;
  const int lane = tid & 63;
  const int lm   = lane & 15;
  const int q    = lane >> 4;
  const int wm   = wave >> 1;
  const int wn   = wave & 1;

  // bijective XCD swizzle over flat block id (nblk % 8 == 0 always)
  const int nblk  = 32 * (int)gridDim.y;
  const int chunk = nblk >> 3;
  int lid = (int)blockIdx.x + 32 * (int)blockIdx.y;
  int swz = (lid & 7) * chunk + (lid >> 3);
  const int zz = swz >> 5;         // (slot*8 + b)
  const int mt = (swz >> 3) & 3;   // M-tile (256 rows)
  const int nt = swz & 7;          // N-tile (128 cols)
  const int b    = zz & 7;
  const int slot = (zz >> 3) % 3;  // %3: identity for real launches (g<=3)

  long arow = (long)slot * 8192 * 768 + ((long)b * 1024 + (long)mt * 256) * 768;
  long brow = ((long)b * 1024 + (long)nt * 128) * 768;

  f32x4 acc[4][4];
  ZERO_ACC(acc);
  mainloop8_3<STGE, CMPU>(Thi + arow, Tlo + arow, 768, nh + brow, nl + brow, 768, lds, acc);

  // epilogue: mask + write fp32 S
  const int br   = br_base + slot;
  const int* adj = (br == 0) ? adj0 : ((br == 1) ? adj1 : adj2);
  const int* adjb = adj + (long)b * 1024 * 1024;
  float* Sb = S + ((long)slot * 8 + b) * 1024 * 1024;
  long row0 = (long)mt * 256 + wm * 64;
  long col0 = (long)nt * 128 + wn * 64;
#pragma unroll
  for (int i = 0; i < 4; ++i)
#pragma unroll
    for (int j = 0; j < 4; ++j)
#pragma unroll
      for (int r = 0; r < 4; ++r) {
        long row = row0 + i * 16 + q * 4 + r;
        long col = col0 + j * 16 + lm;
        float v  = acc[i][j][r];
        v = (adjb[row * 1024 + col] == 1) ? v : -1e7f;
        Sb[row * 1024 + col] = v;
      }
}

// ---- row softmax, WAVE-PER-ROW (4 rows/block, no LDS, no barriers):
//      fp32 S row -> f16 att written IN-PLACE (row stride 2048 f16).
__global__ __launch_bounds__(256) void k_softmax(float* __restrict__ S)
{
  const int wave = threadIdx.x >> 6;
  const int lane = threadIdx.x & 63;
  long row = (long)blockIdx.x * 4 + wave;
  float* rowp = S + row * 1024;
  float4 v[4];
#pragma unroll
  for (int i = 0; i < 4; ++i) v[i] = ((const float4*)rowp)[lane + 64 * i];
  float m = -3e38f;
#pragma unroll
  for (int i = 0; i < 4; ++i)
    m = fmaxf(m, fmaxf(fmaxf(v[i].x, v[i].y), fmaxf(v[i].z, v[i].w)));
#pragma unroll
  for (int off = 32; off; off >>= 1) m = fmaxf(m, __shfl_xor(m, off));
  float e[4][4];
  float s = 0.f;
#pragma unroll
  for (int i = 0; i < 4; ++i) {
    e[i][0] = __expf(v[i].x - m);
    e[i][1] = __expf(v[i].y - m);
    e[i][2] = __expf(v[i].z - m);
    e[i][3] = __expf(v[i].w - m);
    s += e[i][0] + e[i][1] + e[i][2] + e[i][3];
  }
#pragma unroll
  for (int off = 32; off; off >>= 1) s += __shfl_xor(s, off);
  float inv = 1.0f / s;
  f16_t* orow = (f16_t*)rowp;
#pragma unroll
  for (int i = 0; i < 4; ++i) {
    f16x4 o = {(f16_t)(e[i][0] * inv), (f16_t)(e[i][1] * inv),
               (f16_t)(e[i][2] * inv), (f16_t)(e[i][3] * inv)};
    *(f16x4*)(orow + (lane + 64 * i) * 4) = o;
  }
}

// ---------------------------------------------------------------------------
// GEMM-PVF v2 (r4-proven): 128x64 tile, triple-buffered 72 KB, counted
// vmcnt(6). grid (8, 12, 8).
// ---------------------------------------------------------------------------
__global__ __launch_bounds__(256, 2) void k_gemm_pvf(const float* __restrict__ S,
                                                     const f16_t* __restrict__ Vt,
                                                     float* __restrict__ out,
                                                     int g, int br_base)
{
  __shared__ __align__(16) f16_t lds[3 * 12288];   // 72 KB (per buf: A 8192, B 4096 f16)
  const int tid  = threadIdx.x;
  const int wave = tid >> 6;
  const int lane = tid & 63;
  const int lm   = lane & 15;
  const int q    = lane >> 4;
  const int wi   = (wave >> 1) * 64;
  const int wj   = (wave & 1) * 32;
  const int b    = blockIdx.z;
  const int TT   = 16 * g;

  long aoff[4];
  int  adst[4];
#pragma unroll
  for (int i = 0; i < 4; ++i) {
    int c   = i * 256 + tid;       // 1024 chunks: kq*128 + m
    int m   = c & 127;
    int kq  = c >> 7;
    aoff[i] = (long)m * 2048 + kq * 8;
    adst[i] = (i * 256 + wave * 64) * 8;
  }
  long boff[2];
  int  bdst[2];
#pragma unroll
  for (int i = 0; i < 2; ++i) {
    int c   = i * 256 + tid;       // 512 chunks: kq*64 + m
    int m   = c & 63;
    int kq  = c >> 6;
    boff[i] = (long)m * 1024 + kq * 8;
    bdst[i] = 8192 + (i * 256 + wave * 64) * 8;
  }
  const long abase = ((long)b * 1024 + (long)blockIdx.x * 128) * 2048;
  const long bcol  = (long)blockIdx.y * 64 * 1024;

  f32x4 acc[4][2];
#pragma unroll
  for (int i = 0; i < 4; ++i)
#pragma unroll
    for (int j = 0; j < 2; ++j)
      acc[i][j] = (f32x4){0.f, 0.f, 0.f, 0.f};

#define PVF_STAGE(TG, BUF)                                                     \
  {                                                                            \
    int slot_ = (TG) >> 4;                                                     \
    long ko_  = (long)((TG) & 15) * 64;                                        \
    const f16_t* As_ = (const f16_t*)(S + (long)slot_ * 8 * 1024 * 1024) + abase; \
    const f16_t* Bs_ = Vt + (((long)(br_base + slot_) * 8 + b) * 768) * 1024 + bcol; \
    f16_t* L_ = lds + (BUF) * 12288;                                           \
    GLL16(As_ + aoff[0] + ko_, L_ + adst[0]);                                  \
    GLL16(As_ + aoff[1] + ko_, L_ + adst[1]);                                  \
    GLL16(As_ + aoff[2] + ko_, L_ + adst[2]);                                  \
    GLL16(As_ + aoff[3] + ko_, L_ + adst[3]);                                  \
    GLL16(Bs_ + boff[0] + ko_, L_ + bdst[0]);                                  \
    GLL16(Bs_ + boff[1] + ko_, L_ + bdst[1]);                                  \
  }

#define PVF_COMPUTE(BUF)                                                       \
  {                                                                            \
    const f16_t* L_ = lds + (BUF) * 12288;                                     \
    _Pragma("unroll") for (int s2 = 0; s2 < 2; ++s2) {                         \
      f16x8 af[4], bfr[2];                                                     \
      _Pragma("unroll") for (int i = 0; i < 4; ++i)                            \
        af[i] = *(const f16x8*)(L_ + (((s2 * 4 + q) * 128) + wi + i * 16 + lm) * 8); \
      _Pragma("unroll") for (int j = 0; j < 2; ++j)                            \
        bfr[j] = *(const f16x8*)(L_ + 8192 + (((s2 * 4 + q) * 64) + wj + j * 16 + lm) * 8); \
      _Pragma("unroll") for (int i = 0; i < 4; ++i)                            \
        _Pragma("unroll") for (int j = 0; j < 2; ++j)                          \
          acc[i][j] = __builtin_amdgcn_mfma_f32_16x16x32_f16(af[i], bfr[j], acc[i][j], 0, 0, 0); \
    }                                                                          \
  }

  PVF_STAGE(0, 0);
  PVF_STAGE(1, 1);
  asm volatile("s_waitcnt vmcnt(6)" ::: "memory");
  __builtin_amdgcn_s_barrier();

  int buf = 0;
  for (int tg = 0; tg < TT; ++tg) {
    int nb = buf + 2; if (nb >= 3) nb -= 3;
    if (tg + 2 < TT) PVF_STAGE(tg + 2, nb);
    PVF_COMPUTE(buf);
    if (tg + 2 < TT) {
      asm volatile("s_waitcnt vmcnt(6)" ::: "memory");
    } else if (tg + 1 < TT) {
      asm volatile("s_waitcnt vmcnt(0)" ::: "memory");
    }
    __builtin_amdgcn_s_barrier();
    ++buf; if (buf == 3) buf = 0;
  }
#undef PVF_STAGE
#undef PVF_COMPUTE

  float* Cb = out + (long)b * 1024 * 768;
  long row0 = (long)blockIdx.x * 128;
  long col0 = (long)blockIdx.y * 64;
#pragma unroll
  for (int i = 0; i < 4; ++i)
#pragma unroll
    for (int j = 0; j < 2; ++j)
#pragma unroll
      for (int r = 0; r < 4; ++r) {
        long row = row0 + wi + i * 16 + q * 4 + r;
        long col = col0 + wj + j * 16 + lm;
        float v  = acc[i][j][r];
        if (br_base != 0) v += Cb[row * 768 + col];
        Cb[row * 768 + col] = v;
      }
}

extern "C" void kernel_launch(void* const* d_in, const int* in_sizes, int n_in,
                              void* d_out, int out_size, void* d_ws, size_t ws_size,
                              hipStream_t stream)
{
  const float* node    = (const float*)d_in[0];
  const int*   adjp[3] = {(const int*)d_in[1], (const int*)d_in[2], (const int*)d_in[3]};
  const float* Wp[3]   = {(const float*)d_in[4], (const float*)d_in[5], (const float*)d_in[6]};
  const float* params  = (const float*)d_in[7];
  float* out = (float*)d_out;

  const size_t SZ_W3 = 3ull * 768 * 768 * 2;     // f16 [3][768][768]
  const size_t SZ_PT = 768ull * 2304 * 2;        // f16 [768][2304]
  const size_t SZ_N  = 8192ull * 768 * 2;        // f16 [8192][768]
  const size_t SZ_VT = 24ull * 768 * 1024 * 2;   // f16 [3][8][768][1024]
  const size_t SZ_T  = 8192ull * 768 * 2;        // f16 per slot (Thi / Tlo)
  const size_t SZ_S  = 8ull * 1024 * 1024 * 4;   // fp32 per slot (S, later att overlay)
  const size_t FIXED = 2 * SZ_W3 + SZ_PT + 2 * SZ_N + SZ_VT;
  const size_t SLOT  = 2 * SZ_T + SZ_S;

  int NBR = 1;
  if (ws_size >= FIXED + 3 * SLOT) NBR = 3;
  else if (ws_size >= FIXED + 2 * SLOT) NBR = 2;
  else if (ws_size < FIXED + SLOT) return;  // can't run

  char* base = (char*)d_ws;
  size_t off = 0;
  f16_t* Wh      = (f16_t*)(base + off); off += SZ_W3;
  f16_t* Wl      = (f16_t*)(base + off); off += SZ_W3;
  f16_t* paramsT = (f16_t*)(base + off); off += SZ_PT;
  f16_t* node_hi = (f16_t*)(base + off); off += SZ_N;
  f16_t* node_lo = (f16_t*)(base + off); off += SZ_N;
  f16_t* Vt      = (f16_t*)(base + off); off += SZ_VT;
  f16_t* Thi     = (f16_t*)(base + off); off += (size_t)NBR * SZ_T;
  f16_t* Tlo     = (f16_t*)(base + off); off += (size_t)NBR * SZ_T;
  float* S       = (float*)(base + off); off += (size_t)NBR * SZ_S;

  k_cvt_split<<<6144, 256, 0, stream>>>(node, node_hi, node_lo);
  k_transpose_all<<<dim3(24, 72, 4), dim3(32, 8), 0, stream>>>(Wp[0], Wp[1], Wp[2], params,
                                                               Wh, Wl, paramsT);

  // ---- ABLATION PROBES v2 (durations forced into top-5 via grid scaling):
  //  skeleton-only at 3x grid, stage-only at 2x, compute-only at 2x.
  //  All write scratch into S; the real pipeline below overwrites it.
  if (NBR >= 3) {
    k_scores_t<0, 0><<<dim3(32, 72, 1), 512, 0, stream>>>(Thi, Tlo, node_hi, node_lo,
                                                          adjp[0], adjp[1], adjp[2], S, 0);
    k_scores_t<1, 0><<<dim3(32, 48, 1), 512, 0, stream>>>(Thi, Tlo, node_hi, node_lo,
                                                          adjp[0], adjp[1], adjp[2], S, 0);
    k_scores_t<0, 1><<<dim3(32, 48, 1), 512, 0, stream>>>(Thi, Tlo, node_hi, node_lo,
                                                          adjp[0], adjp[1], adjp[2], S, 0);
  }

  int done = 0;
  while (done < 3) {
    int g = (3 - done < NBR) ? (3 - done) : NBR;
    int vtz = (done == 0) ? 3 : 0;
    k_tw_vt<<<dim3(64, 6, g + vtz), 256, 0, stream>>>(node_hi, node_lo, Wh, Wl, paramsT,
                                                      Thi, Tlo, Vt, done, g);
    k_scores_t<1, 1><<<dim3(32, 8 * g, 1), 512, 0, stream>>>(Thi, Tlo, node_hi, node_lo,
                                                             adjp[0], adjp[1], adjp[2], S, done);
    k_softmax<<<2048 * g, 256, 0, stream>>>(S);
    k_gemm_pvf<<<dim3(8, 12, 8), 256, 0, stream>>>(S, Vt, out, g, done);
    done += g;
  }
}

// Round 8
// 523.103 us; speedup vs baseline: 2.5260x; 2.5260x over previous
//
#include <hip/hip_runtime.h>
#include <stdint.h>

typedef _Float16 f16_t;
typedef _Float16 f16x8 __attribute__((ext_vector_type(8)));
typedef _Float16 f16x4 __attribute__((ext_vector_type(4)));
typedef float f32x4 __attribute__((ext_vector_type(4)));

#define GLL16(g, l)                                                                   \
  __builtin_amdgcn_global_load_lds((const __attribute__((address_space(1))) uint32_t*)(g), \
                                   (__attribute__((address_space(3))) uint32_t*)(l),  \
                                   16, 0, 0)

// ---------------------------------------------------------------------------
// PACKED LAYOUTS (r7 finding: strided 16B staging reads = 8x transaction
// amplification = 90% of GEMM time; pack so each GLL16 reads 1KB contiguous).
//   node (8192x768)  -> 64 panels of 128 rows: [panel][kt 0..23][kq 0..3][m 0..127][8]
//                       panel stride 98304 f16, kt block 4096 f16
//   W^T  (3x768x768) -> per z: 6 panels of 128: same geometry, z stride 589824
//   T    (slot,8192x768) -> 32 panels of 256 rows: [panel][kt][kq 0..3][m 0..255][8]
//                       panel stride 196608 f16, kt block 8192 f16
// Chunk order == LDS staging order == what each GLL16 wave consumes.
// ---------------------------------------------------------------------------
#define NP_PANEL 98304L   // 24*4096
#define NP_KT    4096L
#define WP_Z     589824L  // 6*NP_PANEL
#define TP_SLOT  6291456L // 32*TP_PANEL
#define TP_PANEL 196608L  // 24*8192
#define TP_KT    8192L

#define EPI_COORDS                              \
  const int tid  = threadIdx.x;                 \
  const int wave = tid >> 6;                    \
  const int lane = tid & 63;                    \
  const int lm   = lane & 15;                   \
  const int q    = lane >> 4;                   \
  const int wi   = (wave >> 1) * 64;            \
  const int wj   = (wave & 1) * 64;

#define ZERO_ACC(acc)                                            \
  _Pragma("unroll") for (int i = 0; i < 4; ++i)                  \
  _Pragma("unroll") for (int j = 0; j < 4; ++j)                  \
    acc[i][j] = (f32x4){0.f, 0.f, 0.f, 0.f};

// ---------------------------------------------------------------------------
// gemm_tile_pb: 128x128 tile, BK=64, 256 threads. A linear (lda), B PACKED
// (128-row panel, kt64 block = 8192 f16, chunk c = kq*128+m = read offset c*8).
// Used by the vt role (A = paramsT linear, B = packed node).
// ---------------------------------------------------------------------------
__device__ __forceinline__ void gemm_tile_pb(const f16_t* __restrict__ A, long lda,
                                             const f16_t* __restrict__ Bp,
                                             int kTiles, f16_t* lA, f16_t* lB,
                                             f32x4 acc[4][4])
{
  const int tid  = threadIdx.x;
  const int wave = tid >> 6;
  const int lane = tid & 63;

  const f16_t* pA[4];
  const f16_t* pB[4];
  f16_t* lAb[4];
  f16_t* lBb[4];
#pragma unroll
  for (int i = 0; i < 4; ++i) {
    int c  = i * 256 + tid;
    int m  = c & 127;
    int kq = c >> 7;
    pA[i]  = A + (long)m * lda + kq * 8;       // linear A (strided)
    pB[i]  = Bp + (long)c * 8;                 // packed B (contiguous)
    int cb = i * 256 + wave * 64;
    lAb[i] = lA + (long)cb * 8;
    lBb[i] = lB + (long)cb * 8;
  }
  const int lm = lane & 15;
  const int q  = lane >> 4;
  const int wi = (wave >> 1) * 64;
  const int wj = (wave & 1) * 64;

  for (int kt = 0; kt < kTiles; ++kt) {
    long koA = (long)kt * 64;
    long koB = (long)kt * 8192;
#pragma unroll
    for (int i = 0; i < 4; ++i) GLL16(pA[i] + koA, lAb[i]);
#pragma unroll
    for (int i = 0; i < 4; ++i) GLL16(pB[i] + koB, lBb[i]);
    __syncthreads();
#pragma unroll
    for (int s = 0; s < 2; ++s) {
      f16x8 af[4], bfr[4];
#pragma unroll
      for (int i = 0; i < 4; ++i)
        af[i] = *(const f16x8*)(lA + (((s * 4 + q) * 128) + wi + i * 16 + lm) * 8);
#pragma unroll
      for (int j = 0; j < 4; ++j)
        bfr[j] = *(const f16x8*)(lB + (((s * 4 + q) * 128) + wj + j * 16 + lm) * 8);
#pragma unroll
      for (int i = 0; i < 4; ++i)
#pragma unroll
        for (int j = 0; j < 4; ++j)
          acc[i][j] = __builtin_amdgcn_mfma_f32_16x16x32_f16(af[i], bfr[j], acc[i][j], 0, 0, 0);
    }
    __syncthreads();
  }
}

// ---------------------------------------------------------------------------
// gemm_tile3_p: fused hi/lo 3-product, BK=32, 256 threads, BOTH operands
// packed 128-row panels (kt block 4096 f16). Used by the tw role.
// Accumulation order identical to the proven gemm_tile3.
// ---------------------------------------------------------------------------
__device__ __forceinline__ void gemm_tile3_p(const f16_t* __restrict__ Ahp,
                                             const f16_t* __restrict__ Alp,
                                             const f16_t* __restrict__ Bhp,
                                             const f16_t* __restrict__ Blp,
                                             int kTiles,
                                             f16_t* lAh, f16_t* lAl,
                                             f16_t* lBh, f16_t* lBl,
                                             f32x4 acc[4][4])
{
  const int tid  = threadIdx.x;
  const int wave = tid >> 6;
  const int lane = tid & 63;

  const f16_t* pAh[2]; const f16_t* pAl[2];
  const f16_t* pBh[2]; const f16_t* pBl[2];
  f16_t* dAh[2]; f16_t* dAl[2]; f16_t* dBh[2]; f16_t* dBl[2];
#pragma unroll
  for (int i = 0; i < 2; ++i) {
    int c  = i * 256 + tid;        // chunk 0..511 (kq*128+m)
    pAh[i] = Ahp + (long)c * 8;  pAl[i] = Alp + (long)c * 8;
    pBh[i] = Bhp + (long)c * 8;  pBl[i] = Blp + (long)c * 8;
    int cb = i * 256 + wave * 64;
    dAh[i] = lAh + (long)cb * 8;  dAl[i] = lAl + (long)cb * 8;
    dBh[i] = lBh + (long)cb * 8;  dBl[i] = lBl + (long)cb * 8;
  }
  const int lm = lane & 15;
  const int q  = lane >> 4;
  const int wi = (wave >> 1) * 64;
  const int wj = (wave & 1) * 64;

  for (int kt = 0; kt < kTiles; ++kt) {
    long ko = (long)kt * NP_KT;
#pragma unroll
    for (int i = 0; i < 2; ++i) GLL16(pAh[i] + ko, dAh[i]);
#pragma unroll
    for (int i = 0; i < 2; ++i) GLL16(pAl[i] + ko, dAl[i]);
#pragma unroll
    for (int i = 0; i < 2; ++i) GLL16(pBh[i] + ko, dBh[i]);
#pragma unroll
    for (int i = 0; i < 2; ++i) GLL16(pBl[i] + ko, dBl[i]);
    __syncthreads();
    {
      f16x8 ah[4], al[4], bh[4], bl[4];
#pragma unroll
      for (int i = 0; i < 4; ++i)
        ah[i] = *(const f16x8*)(lAh + (q * 128 + wi + i * 16 + lm) * 8);
#pragma unroll
      for (int j = 0; j < 4; ++j)
        bh[j] = *(const f16x8*)(lBh + (q * 128 + wj + j * 16 + lm) * 8);
#pragma unroll
      for (int i = 0; i < 4; ++i)
#pragma unroll
        for (int j = 0; j < 4; ++j)
          acc[i][j] = __builtin_amdgcn_mfma_f32_16x16x32_f16(ah[i], bh[j], acc[i][j], 0, 0, 0);
#pragma unroll
      for (int i = 0; i < 4; ++i)
        al[i] = *(const f16x8*)(lAl + (q * 128 + wi + i * 16 + lm) * 8);
#pragma unroll
      for (int i = 0; i < 4; ++i)
#pragma unroll
        for (int j = 0; j < 4; ++j)
          acc[i][j] = __builtin_amdgcn_mfma_f32_16x16x32_f16(al[i], bh[j], acc[i][j], 0, 0, 0);
#pragma unroll
      for (int j = 0; j < 4; ++j)
        bl[j] = *(const f16x8*)(lBl + (q * 128 + wj + j * 16 + lm) * 8);
#pragma unroll
      for (int i = 0; i < 4; ++i)
#pragma unroll
        for (int j = 0; j < 4; ++j)
          acc[i][j] = __builtin_amdgcn_mfma_f32_16x16x32_f16(ah[i], bl[j], acc[i][j], 0, 0, 0);
    }
    __syncthreads();
  }
}

// ---------------------------------------------------------------------------
// Scores 4-phase mainloop (r4-best skeleton), PACKED operands:
// A = packed T (256-row panel, kt block 8192), B = packed node (128-row panel,
// kt block 4096). Triple-buffered 144 KB, counted vmcnt(6).
// ---------------------------------------------------------------------------

#define SC8_MFMA_QUAD(i0, j0)                                                   \
  __builtin_amdgcn_s_setprio(1);                                                \
  _Pragma("unroll") for (int ii = 0; ii < 2; ++ii)                              \
  _Pragma("unroll") for (int jj = 0; jj < 2; ++jj) {                            \
    acc[(i0)+ii][(j0)+jj] = __builtin_amdgcn_mfma_f32_16x16x32_f16(             \
        ah[(i0)+ii], bh[(j0)+jj], acc[(i0)+ii][(j0)+jj], 0, 0, 0);              \
    acc[(i0)+ii][(j0)+jj] = __builtin_amdgcn_mfma_f32_16x16x32_f16(             \
        al[(i0)+ii], bh[(j0)+jj], acc[(i0)+ii][(j0)+jj], 0, 0, 0);              \
    acc[(i0)+ii][(j0)+jj] = __builtin_amdgcn_mfma_f32_16x16x32_f16(             \
        ah[(i0)+ii], bl[(j0)+jj], acc[(i0)+ii][(j0)+jj], 0, 0, 0);              \
  }                                                                             \
  __builtin_amdgcn_s_setprio(0);

#define SC8_RD_A(lb, i)                                                \
  ah[i] = *(const f16x8*)((lb) + raA + (i) * 128);                     \
  al[i] = *(const f16x8*)((lb) + 8192 + raA + (i) * 128);
#define SC8_RD_B(lb, j)                                                \
  bh[j] = *(const f16x8*)((lb) + 16384 + rbB + (j) * 128);             \
  bl[j] = *(const f16x8*)((lb) + 20480 + rbB + (j) * 128);

#define SC8_BAR_LGKM                                                   \
  __builtin_amdgcn_s_barrier();                                        \
  asm volatile("s_waitcnt lgkmcnt(0)" ::: "memory");

#define SC8_STAGE_TILE(nb, T)                                    \
  {                                                              \
    long koA = (long)(T) * TP_KT;                                \
    long koB = (long)(T) * NP_KT;                                \
    GLL16(pAh0 + koA, (nb) + dA0);                               \
    GLL16(pAh1 + koA, (nb) + dA1);                               \
    GLL16(pAl0 + koA, (nb) + 8192 + dA0);                        \
    GLL16(pAl1 + koA, (nb) + 8192 + dA1);                        \
    GLL16(pBh + koB, (nb) + 16384 + dB);                         \
    GLL16(pBl + koB, (nb) + 20480 + dB);                         \
  }

#define SC8_TILE(LB, NB, T, ST)                                                 \
  {                                                                             \
    const f16_t* lb = (LB);                                                     \
    f16_t* nb = (NB);                                                           \
    const long koA = (long)((T) + 2) * TP_KT;                                   \
    const long koB = (long)((T) + 2) * NP_KT;                                   \
    f16x8 ah[4], al[4], bh[4], bl[4];                                           \
    SC8_RD_A(lb, 0); SC8_RD_A(lb, 1); SC8_RD_B(lb, 0); SC8_RD_B(lb, 1);         \
    if (ST) { GLL16(pAh0 + koA, nb + dA0); GLL16(pAh1 + koA, nb + dA1); }       \
    SC8_BAR_LGKM;                                                               \
    SC8_MFMA_QUAD(0, 0);                                                        \
    __builtin_amdgcn_s_barrier();                                               \
    SC8_RD_B(lb, 2); SC8_RD_B(lb, 3);                                           \
    if (ST) { GLL16(pAl0 + koA, nb + 8192 + dA0); GLL16(pAl1 + koA, nb + 8192 + dA1); } \
    SC8_BAR_LGKM;                                                               \
    SC8_MFMA_QUAD(0, 2);                                                        \
    __builtin_amdgcn_s_barrier();                                               \
    SC8_RD_A(lb, 2); SC8_RD_A(lb, 3);                                           \
    if (ST) GLL16(pBh + koB, nb + 16384 + dB);                                  \
    SC8_BAR_LGKM;                                                               \
    SC8_MFMA_QUAD(2, 2);                                                        \
    __builtin_amdgcn_s_barrier();                                               \
    if (ST) GLL16(pBl + koB, nb + 20480 + dB);                                  \
    SC8_BAR_LGKM;                                                               \
    SC8_MFMA_QUAD(2, 0);                                                        \
  }

#define SC8_WAIT6_BAR                                                  \
  asm volatile("s_waitcnt vmcnt(6)" ::: "memory");                     \
  __builtin_amdgcn_s_barrier();
#define SC8_WAIT0_BAR                                                  \
  asm volatile("s_waitcnt vmcnt(0)" ::: "memory");                     \
  __builtin_amdgcn_s_barrier();

__device__ __forceinline__ void mainloop8_3p(const f16_t* __restrict__ Ahp,
                                             const f16_t* __restrict__ Alp,
                                             const f16_t* __restrict__ Bhp,
                                             const f16_t* __restrict__ Blp,
                                             f16_t* lds, f32x4 acc[4][4])
{
  f16_t* bu0 = lds;
  f16_t* bu1 = lds + 24576;
  f16_t* bu2 = lds + 49152;

  const int tid  = threadIdx.x;
  const int wave = tid >> 6;
  const int lane = tid & 63;
  const int lm   = lane & 15;
  const int q    = lane >> 4;
  const int wm   = wave >> 1;   // 0..3  (M)
  const int wn   = wave & 1;    // 0..1  (N)

  // packed staging: A chunks (kq*256+m): thread covers c=tid and c=tid+512.
  const f16_t* pAh0 = Ahp + (long)tid * 8;
  const f16_t* pAh1 = Ahp + (long)(tid + 512) * 8;
  const f16_t* pAl0 = Alp + (long)tid * 8;
  const f16_t* pAl1 = Alp + (long)(tid + 512) * 8;
  // B chunks (kq*128+m): thread covers c=tid.
  const f16_t* pBh = Bhp + (long)tid * 8;
  const f16_t* pBl = Blp + (long)tid * 8;
  const int dA0 = wave * 512;
  const int dA1 = 4096 + wave * 512;
  const int dB  = wave * 512;

  const int raA = (q * 256 + wm * 64 + lm) * 8;
  const int rbB = (q * 128 + wn * 64 + lm) * 8;

  SC8_STAGE_TILE(bu0, 0);
  SC8_STAGE_TILE(bu1, 1);
  SC8_WAIT6_BAR;

  for (int it = 0; it < 7; ++it) {
    int t0 = it * 3;
    SC8_TILE(bu0, bu2, t0, 1);     SC8_WAIT6_BAR;
    SC8_TILE(bu1, bu0, t0 + 1, 1); SC8_WAIT6_BAR;
    SC8_TILE(bu2, bu1, t0 + 2, 1); SC8_WAIT6_BAR;
  }
  SC8_TILE(bu0, bu2, 21, 1); SC8_WAIT6_BAR;
  SC8_TILE(bu1, bu0, 22, 0); SC8_WAIT0_BAR;
  SC8_TILE(bu2, bu1, 23, 0);
}

// ---- convert fp32 node -> PACKED f16 hi/lo. grid (24 kt, 64 panels), 256 thr.
//      Writes are fully contiguous 1KB/wave; reads 32B-strided (one-shot).
__global__ __launch_bounds__(256) void k_cvt_split(const float* __restrict__ src,
                                                   f16_t* __restrict__ hi,
                                                   f16_t* __restrict__ lo)
{
  const int kt    = blockIdx.x;
  const int panel = blockIdx.y;
  const int t     = threadIdx.x;
  long pbase = ((long)panel * 24 + kt) * NP_KT;
#pragma unroll
  for (int i = 0; i < 2; ++i) {
    int c  = i * 256 + t;        // chunk kq*128+m
    int m  = c & 127;
    int kq = c >> 7;
    const float* sp = src + ((long)panel * 128 + m) * 768 + kt * 32 + kq * 8;
    float4 u = *(const float4*)sp;
    float4 w = *(const float4*)(sp + 4);
    f16_t h0 = (f16_t)u.x, h1 = (f16_t)u.y, h2 = (f16_t)u.z, h3 = (f16_t)u.w;
    f16_t h4 = (f16_t)w.x, h5 = (f16_t)w.y, h6 = (f16_t)w.z, h7 = (f16_t)w.w;
    f16x8 hv = {h0, h1, h2, h3, h4, h5, h6, h7};
    f16x8 lv = {(f16_t)(u.x - (float)h0), (f16_t)(u.y - (float)h1),
                (f16_t)(u.z - (float)h2), (f16_t)(u.w - (float)h3),
                (f16_t)(w.x - (float)h4), (f16_t)(w.y - (float)h5),
                (f16_t)(w.z - (float)h6), (f16_t)(w.w - (float)h7)};
    *(f16x8*)(hi + pbase + (long)c * 8) = hv;
    *(f16x8*)(lo + pbase + (long)c * 8) = lv;
  }
}

// ---- merged transposes: z<3 -> W branch z PACKED (hi+lo); z==3 -> params (linear)
__global__ __launch_bounds__(256) void k_transpose_all(const float* __restrict__ w0,
                                                       const float* __restrict__ w1,
                                                       const float* __restrict__ w2,
                                                       const float* __restrict__ params,
                                                       f16_t* __restrict__ Wh,
                                                       f16_t* __restrict__ Wl,
                                                       f16_t* __restrict__ paramsT)
{
  __shared__ float t[32][33];
  const int z = blockIdx.z;
  const float* src;
  int C;
  if (z < 3) {
    if (blockIdx.y >= 24) return;
    src = (z == 0) ? w0 : ((z == 1) ? w1 : w2);
    C = 768;
  } else {
    src = params;
    C = 768;
  }
  int x = blockIdx.x * 32 + threadIdx.x;
  int y = blockIdx.y * 32 + threadIdx.y;
#pragma unroll
  for (int j = 0; j < 32; j += 8)
    t[threadIdx.y + j][threadIdx.x] = src[(long)(y + j) * C + x];
  __syncthreads();
  int x2 = blockIdx.y * 32 + threadIdx.x;
  int y2 = blockIdx.x * 32 + threadIdx.y;
  if (z < 3) {
    f16_t* hi = Wh + (long)z * WP_Z;
    f16_t* lo = Wl + (long)z * WP_Z;
#pragma unroll
    for (int j = 0; j < 32; j += 8) {
      float v  = t[threadIdx.x][threadIdx.y + j];
      int row = y2 + j;            // 0..767 (transposed row)
      int col = x2;                // 0..767
      f16_t h  = (f16_t)v;
      long off = (long)(row >> 7) * NP_PANEL + (long)(col >> 5) * NP_KT +
                 (long)((col >> 3) & 3) * 1024 + (long)(row & 127) * 8 + (col & 7);
      hi[off] = h;
      lo[off] = (f16_t)(v - (float)h);
    }
  } else {
#pragma unroll
    for (int j = 0; j < 32; j += 8) {
      float v  = t[threadIdx.x][threadIdx.y + j];
      long idx = (long)(y2 + j) * 2304 + x2;
      paramsT[idx] = (f16_t)v;
    }
  }
}

// ---- merged tw + vt dispatch. z < g: tw slot z (packed A=node, packed B=W,
//      packed T output). z >= g: vt (A=paramsT linear, B=packed node).
__global__ __launch_bounds__(256, 4) void k_tw_vt(const f16_t* __restrict__ nh,
                                                  const f16_t* __restrict__ nl,
                                                  const f16_t* __restrict__ Wh,
                                                  const f16_t* __restrict__ Wl,
                                                  const f16_t* __restrict__ paramsT,
                                                  f16_t* __restrict__ Thi,
                                                  f16_t* __restrict__ Tlo,
                                                  f16_t* __restrict__ Vt,
                                                  int br_base, int g)
{
  __shared__ __align__(16) f16_t lds[16384];   // 32 KB, shared by both roles
  if ((int)blockIdx.z < g) {
    f32x4 acc[4][4];
    ZERO_ACC(acc);
    const int slot = blockIdx.z;
    const long br  = br_base + slot;
    const f16_t* Ahp = nh + (long)blockIdx.x * NP_PANEL;
    const f16_t* Alp = nl + (long)blockIdx.x * NP_PANEL;
    const f16_t* Bhp = Wh + br * WP_Z + (long)blockIdx.y * NP_PANEL;
    const f16_t* Blp = Wl + br * WP_Z + (long)blockIdx.y * NP_PANEL;
    gemm_tile3_p(Ahp, Alp, Bhp, Blp, 24,
                 lds, lds + 4096, lds + 8192, lds + 12288, acc);
    EPI_COORDS;
    long out0 = (long)slot * TP_SLOT;
    long row0 = (long)blockIdx.x * 128;
    long col0 = (long)blockIdx.y * 128;
#pragma unroll
    for (int i = 0; i < 4; ++i)
#pragma unroll
      for (int j = 0; j < 4; ++j)
#pragma unroll
        for (int r = 0; r < 4; ++r) {
          long row = row0 + wi + i * 16 + q * 4 + r;
          long col = col0 + wj + j * 16 + lm;
          float v  = acc[i][j][r];
          f16_t h  = (f16_t)v;
          long off = out0 + (row >> 8) * TP_PANEL + (col >> 5) * TP_KT +
                     ((col >> 3) & 3) * 2048 + (row & 255) * 8 + (col & 7);
          Thi[off] = h;
          Tlo[off] = (f16_t)(v - (float)h);
        }
  } else {
    int id   = blockIdx.x + 64 * (blockIdx.y + 6 * (blockIdx.z - g));  // 0..1151
    int vx   = id % 6;
    int rest = id / 6;
    int vy   = rest & 7;
    int vz   = rest >> 3;        // 0..23
    int b    = vz & 7;
    int br   = vz >> 3;
    f32x4 acc[4][4];
    ZERO_ACC(acc);
    const f16_t* A  = paramsT + (long)vx * 128 * 2304 + (long)br * 768;
    const f16_t* Bp = nh + (long)(b * 8 + vy) * NP_PANEL;
    gemm_tile_pb(A, 2304, Bp, 12, lds, lds + 8192, acc);
    EPI_COORDS;
    f16_t* C = Vt + ((long)(br * 8 + b) * 768) * 1024;
    long row0 = (long)vx * 128;
    long col0 = (long)vy * 128;
#pragma unroll
    for (int i = 0; i < 4; ++i)
#pragma unroll
      for (int j = 0; j < 4; ++j)
#pragma unroll
        for (int r = 0; r < 4; ++r) {
          long row = row0 + wi + i * 16 + q * 4 + r;
          long col = col0 + wj + j * 16 + lm;
          C[row * 1024 + col] = (f16_t)acc[i][j][r];
        }
  }
}

// ---------------------------------------------------------------------------
// 4-phase scores kernel, packed operands.
// ---------------------------------------------------------------------------
__global__ __launch_bounds__(512, 2) void k_gemm_scores8(const f16_t* __restrict__ Thi,
                                                         const f16_t* __restrict__ Tlo,
                                                         const f16_t* __restrict__ nh,
                                                         const f16_t* __restrict__ nl,
                                                         const int* __restrict__ adj0,
                                                         const int* __restrict__ adj1,
                                                         const int* __restrict__ adj2,
                                                         float* __restrict__ S, int br_base)
{
  __shared__ __align__(16) f16_t lds[3 * 24576];   // 144 KB

  const int tid  = threadIdx.x;
  const int wave = tid >> 6;
  const int lane = tid & 63;
  const int lm   = lane & 15;
  const int q    = lane >> 4;
  const int wm   = wave >> 1;
  const int wn   = wave & 1;

  // bijective XCD swizzle over flat block id (nblk % 8 == 0 always)
  const int nblk  = 32 * (int)gridDim.y;
  const int chunk = nblk >> 3;
  int lid = (int)blockIdx.x + 32 * (int)blockIdx.y;
  int swz = (lid & 7) * chunk + (lid >> 3);
  const int zz = swz >> 5;         // (slot*8 + b)
  const int mt = (swz >> 3) & 3;   // M-tile (256 rows)
  const int nt = swz & 7;          // N-tile (128 cols)
  const int b    = zz & 7;
  const int slot = zz >> 3;

  const f16_t* Ahp = Thi + (long)slot * TP_SLOT + (long)(b * 4 + mt) * TP_PANEL;
  const f16_t* Alp = Tlo + (long)slot * TP_SLOT + (long)(b * 4 + mt) * TP_PANEL;
  const f16_t* Bhp = nh + (long)(b * 8 + nt) * NP_PANEL;
  const f16_t* Blp = nl + (long)(b * 8 + nt) * NP_PANEL;

  f32x4 acc[4][4];
  ZERO_ACC(acc);
  mainloop8_3p(Ahp, Alp, Bhp, Blp, lds, acc);

  // epilogue: mask + write fp32 S
  const int br   = br_base + slot;
  const int* adj = (br == 0) ? adj0 : ((br == 1) ? adj1 : adj2);
  const int* adjb = adj + (long)b * 1024 * 1024;
  float* Sb = S + ((long)slot * 8 + b) * 1024 * 1024;
  long row0 = (long)mt * 256 + wm * 64;
  long col0 = (long)nt * 128 + wn * 64;
#pragma unroll
  for (int i = 0; i < 4; ++i)
#pragma unroll
    for (int j = 0; j < 4; ++j)
#pragma unroll
      for (int r = 0; r < 4; ++r) {
        long row = row0 + i * 16 + q * 4 + r;
        long col = col0 + j * 16 + lm;
        float v  = acc[i][j][r];
        v = (adjb[row * 1024 + col] == 1) ? v : -1e7f;
        Sb[row * 1024 + col] = v;
      }
}

// ---- row softmax, WAVE-PER-ROW (4 rows/block, no LDS, no barriers):
//      fp32 S row -> f16 att written IN-PLACE (row stride 2048 f16).
__global__ __launch_bounds__(256) void k_softmax(float* __restrict__ S)
{
  const int wave = threadIdx.x >> 6;
  const int lane = threadIdx.x & 63;
  long row = (long)blockIdx.x * 4 + wave;
  float* rowp = S + row * 1024;
  float4 v[4];
#pragma unroll
  for (int i = 0; i < 4; ++i) v[i] = ((const float4*)rowp)[lane + 64 * i];
  float m = -3e38f;
#pragma unroll
  for (int i = 0; i < 4; ++i)
    m = fmaxf(m, fmaxf(fmaxf(v[i].x, v[i].y), fmaxf(v[i].z, v[i].w)));
#pragma unroll
  for (int off = 32; off; off >>= 1) m = fmaxf(m, __shfl_xor(m, off));
  float e[4][4];
  float s = 0.f;
#pragma unroll
  for (int i = 0; i < 4; ++i) {
    e[i][0] = __expf(v[i].x - m);
    e[i][1] = __expf(v[i].y - m);
    e[i][2] = __expf(v[i].z - m);
    e[i][3] = __expf(v[i].w - m);
    s += e[i][0] + e[i][1] + e[i][2] + e[i][3];
  }
#pragma unroll
  for (int off = 32; off; off >>= 1) s += __shfl_xor(s, off);
  float inv = 1.0f / s;
  f16_t* orow = (f16_t*)rowp;
#pragma unroll
  for (int i = 0; i < 4; ++i) {
    f16x4 o = {(f16_t)(e[i][0] * inv), (f16_t)(e[i][1] * inv),
               (f16_t)(e[i][2] * inv), (f16_t)(e[i][3] * inv)};
    *(f16x4*)(orow + (lane + 64 * i) * 4) = o;
  }
}

// ---------------------------------------------------------------------------
// GEMM-PVF v2 (r4-proven): 128x64 tile, triple-buffered 72 KB, counted
// vmcnt(6). grid (8, 12, 8). (S/Vt stay linear this round.)
// ---------------------------------------------------------------------------
__global__ __launch_bounds__(256, 2) void k_gemm_pvf(const float* __restrict__ S,
                                                     const f16_t* __restrict__ Vt,
                                                     float* __restrict__ out,
                                                     int g, int br_base)
{
  __shared__ __align__(16) f16_t lds[3 * 12288];   // 72 KB (per buf: A 8192, B 4096 f16)
  const int tid  = threadIdx.x;
  const int wave = tid >> 6;
  const int lane = tid & 63;
  const int lm   = lane & 15;
  const int q    = lane >> 4;
  const int wi   = (wave >> 1) * 64;
  const int wj   = (wave & 1) * 32;
  const int b    = blockIdx.z;
  const int TT   = 16 * g;

  long aoff[4];
  int  adst[4];
#pragma unroll
  for (int i = 0; i < 4; ++i) {
    int c   = i * 256 + tid;       // 1024 chunks: kq*128 + m
    int m   = c & 127;
    int kq  = c >> 7;
    aoff[i] = (long)m * 2048 + kq * 8;
    adst[i] = (i * 256 + wave * 64) * 8;
  }
  long boff[2];
  int  bdst[2];
#pragma unroll
  for (int i = 0; i < 2; ++i) {
    int c   = i * 256 + tid;       // 512 chunks: kq*64 + m
    int m   = c & 63;
    int kq  = c >> 6;
    boff[i] = (long)m * 1024 + kq * 8;
    bdst[i] = 8192 + (i * 256 + wave * 64) * 8;
  }
  const long abase = ((long)b * 1024 + (long)blockIdx.x * 128) * 2048;
  const long bcol  = (long)blockIdx.y * 64 * 1024;

  f32x4 acc[4][2];
#pragma unroll
  for (int i = 0; i < 4; ++i)
#pragma unroll
    for (int j = 0; j < 2; ++j)
      acc[i][j] = (f32x4){0.f, 0.f, 0.f, 0.f};

#define PVF_STAGE(TG, BUF)                                                     \
  {                                                                            \
    int slot_ = (TG) >> 4;                                                     \
    long ko_  = (long)((TG) & 15) * 64;                                        \
    const f16_t* As_ = (const f16_t*)(S + (long)slot_ * 8 * 1024 * 1024) + abase; \
    const f16_t* Bs_ = Vt + (((long)(br_base + slot_) * 8 + b) * 768) * 1024 + bcol; \
    f16_t* L_ = lds + (BUF) * 12288;                                           \
    GLL16(As_ + aoff[0] + ko_, L_ + adst[0]);                                  \
    GLL16(As_ + aoff[1] + ko_, L_ + adst[1]);                                  \
    GLL16(As_ + aoff[2] + ko_, L_ + adst[2]);                                  \
    GLL16(As_ + aoff[3] + ko_, L_ + adst[3]);                                  \
    GLL16(Bs_ + boff[0] + ko_, L_ + bdst[0]);                                  \
    GLL16(Bs_ + boff[1] + ko_, L_ + bdst[1]);                                  \
  }

#define PVF_COMPUTE(BUF)                                                       \
  {                                                                            \
    const f16_t* L_ = lds + (BUF) * 12288;                                     \
    _Pragma("unroll") for (int s2 = 0; s2 < 2; ++s2) {                         \
      f16x8 af[4], bfr[2];                                                     \
      _Pragma("unroll") for (int i = 0; i < 4; ++i)                            \
        af[i] = *(const f16x8*)(L_ + (((s2 * 4 + q) * 128) + wi + i * 16 + lm) * 8); \
      _Pragma("unroll") for (int j = 0; j < 2; ++j)                            \
        bfr[j] = *(const f16x8*)(L_ + 8192 + (((s2 * 4 + q) * 64) + wj + j * 16 + lm) * 8); \
      _Pragma("unroll") for (int i = 0; i < 4; ++i)                            \
        _Pragma("unroll") for (int j = 0; j < 2; ++j)                          \
          acc[i][j] = __builtin_amdgcn_mfma_f32_16x16x32_f16(af[i], bfr[j], acc[i][j], 0, 0, 0); \
    }                                                                          \
  }

  PVF_STAGE(0, 0);
  PVF_STAGE(1, 1);
  asm volatile("s_waitcnt vmcnt(6)" ::: "memory");
  __builtin_amdgcn_s_barrier();

  int buf = 0;
  for (int tg = 0; tg < TT; ++tg) {
    int nb = buf + 2; if (nb >= 3) nb -= 3;
    if (tg + 2 < TT) PVF_STAGE(tg + 2, nb);
    PVF_COMPUTE(buf);
    if (tg + 2 < TT) {
      asm volatile("s_waitcnt vmcnt(6)" ::: "memory");
    } else if (tg + 1 < TT) {
      asm volatile("s_waitcnt vmcnt(0)" ::: "memory");
    }
    __builtin_amdgcn_s_barrier();
    ++buf; if (buf == 3) buf = 0;
  }
#undef PVF_STAGE
#undef PVF_COMPUTE

  float* Cb = out + (long)b * 1024 * 768;
  long row0 = (long)blockIdx.x * 128;
  long col0 = (long)blockIdx.y * 64;
#pragma unroll
  for (int i = 0; i < 4; ++i)
#pragma unroll
    for (int j = 0; j < 2; ++j)
#pragma unroll
      for (int r = 0; r < 4; ++r) {
        long row = row0 + wi + i * 16 + q * 4 + r;
        long col = col0 + wj + j * 16 + lm;
        float v  = acc[i][j][r];
        if (br_base != 0) v += Cb[row * 768 + col];
        Cb[row * 768 + col] = v;
      }
}

extern "C" void kernel_launch(void* const* d_in, const int* in_sizes, int n_in,
                              void* d_out, int out_size, void* d_ws, size_t ws_size,
                              hipStream_t stream)
{
  const float* node    = (const float*)d_in[0];
  const int*   adjp[3] = {(const int*)d_in[1], (const int*)d_in[2], (const int*)d_in[3]};
  const float* Wp[3]   = {(const float*)d_in[4], (const float*)d_in[5], (const float*)d_in[6]};
  const float* params  = (const float*)d_in[7];
  float* out = (float*)d_out;

  const size_t SZ_W3 = 3ull * 768 * 768 * 2;     // f16 [3] packed W
  const size_t SZ_PT = 768ull * 2304 * 2;        // f16 [768][2304] linear
  const size_t SZ_N  = 8192ull * 768 * 2;        // f16 packed node
  const size_t SZ_VT = 24ull * 768 * 1024 * 2;   // f16 [3][8][768][1024] linear
  const size_t SZ_T  = 8192ull * 768 * 2;        // f16 per slot packed T
  const size_t SZ_S  = 8ull * 1024 * 1024 * 4;   // fp32 per slot
  const size_t FIXED = 2 * SZ_W3 + SZ_PT + 2 * SZ_N + SZ_VT;
  const size_t SLOT  = 2 * SZ_T + SZ_S;

  int NBR = 1;
  if (ws_size >= FIXED + 3 * SLOT) NBR = 3;
  else if (ws_size >= FIXED + 2 * SLOT) NBR = 2;
  else if (ws_size < FIXED + SLOT) return;  // can't run

  char* base = (char*)d_ws;
  size_t off = 0;
  f16_t* Wh      = (f16_t*)(base + off); off += SZ_W3;
  f16_t* Wl      = (f16_t*)(base + off); off += SZ_W3;
  f16_t* paramsT = (f16_t*)(base + off); off += SZ_PT;
  f16_t* node_hi = (f16_t*)(base + off); off += SZ_N;
  f16_t* node_lo = (f16_t*)(base + off); off += SZ_N;
  f16_t* Vt      = (f16_t*)(base + off); off += SZ_VT;
  f16_t* Thi     = (f16_t*)(base + off); off += (size_t)NBR * SZ_T;
  f16_t* Tlo     = (f16_t*)(base + off); off += (size_t)NBR * SZ_T;
  float* S       = (float*)(base + off); off += (size_t)NBR * SZ_S;

  k_cvt_split<<<dim3(24, 64, 1), 256, 0, stream>>>(node, node_hi, node_lo);
  k_transpose_all<<<dim3(24, 72, 4), dim3(32, 8), 0, stream>>>(Wp[0], Wp[1], Wp[2], params,
                                                               Wh, Wl, paramsT);

  int done = 0;
  while (done < 3) {
    int g = (3 - done < NBR) ? (3 - done) : NBR;
    int vtz = (done == 0) ? 3 : 0;
    k_tw_vt<<<dim3(64, 6, g + vtz), 256, 0, stream>>>(node_hi, node_lo, Wh, Wl, paramsT,
                                                      Thi, Tlo, Vt, done, g);
    k_gemm_scores8<<<dim3(32, 8 * g, 1), 512, 0, stream>>>(Thi, Tlo, node_hi, node_lo,
                                                           adjp[0], adjp[1], adjp[2], S, done);
    k_softmax<<<2048 * g, 256, 0, stream>>>(S);
    k_gemm_pvf<<<dim3(8, 12, 8), 256, 0, stream>>>(S, Vt, out, g, done);
    done += g;
  }
}

// Round 9
// 472.779 us; speedup vs baseline: 2.7949x; 1.1064x over previous
//
#include <hip/hip_runtime.h>
#include <stdint.h>

typedef _Float16 f16_t;
typedef _Float16 f16x8 __attribute__((ext_vector_type(8)));
typedef _Float16 f16x4 __attribute__((ext_vector_type(4)));
typedef float f32x4 __attribute__((ext_vector_type(4)));

#define GLL16(g, l)                                                                   \
  __builtin_amdgcn_global_load_lds((const __attribute__((address_space(1))) uint32_t*)(g), \
                                   (__attribute__((address_space(3))) uint32_t*)(l),  \
                                   16, 0, 0)

// ---------------------------------------------------------------------------
// PACKED LAYOUTS (r7/r8 finding: strided 16B staging reads = 8x transaction
// amplification; pack so each GLL16 wave reads full 128B lines).
//   node (8192x768)  -> 64 panels of 128 rows: [panel][kt 0..23][kq 0..3][m 0..127][8]
//   W^T  (3x768x768) -> per z: 6 panels of 128: same geometry
//   T    (slot,8192x768) -> 32 panels of 256 rows: [panel][kt][kq 0..3][m 0..255][8]
//   paramsT (768x2304) -> [vx 0..5][br 0..2][kt 0..11][kq*128+m][8]  (NEW r9)
// att (S overlay) and Vt stay linear; pvf uses the both-sides XOR swizzle
// (rule #21): linear LDS, pre-swizzled global source, swizzled ds_read.
// ---------------------------------------------------------------------------
#define NP_PANEL 98304L   // 24*4096
#define NP_KT    4096L
#define WP_Z     589824L  // 6*NP_PANEL
#define TP_SLOT  6291456L // 32*TP_PANEL
#define TP_PANEL 196608L  // 24*8192
#define TP_KT    8192L
#define PT_VXBR  98304L   // 12*8192 (paramsT packed: per (vx,br) block)

#define EPI_COORDS                              \
  const int tid  = threadIdx.x;                 \
  const int wave = tid >> 6;                    \
  const int lane = tid & 63;                    \
  const int lm   = lane & 15;                   \
  const int q    = lane >> 4;                   \
  const int wi   = (wave >> 1) * 64;            \
  const int wj   = (wave & 1) * 64;

#define ZERO_ACC(acc)                                            \
  _Pragma("unroll") for (int i = 0; i < 4; ++i)                  \
  _Pragma("unroll") for (int j = 0; j < 4; ++j)                  \
    acc[i][j] = (f32x4){0.f, 0.f, 0.f, 0.f};

// ---------------------------------------------------------------------------
// gemm_tile_pp: 128x128 tile, BK=64, 256 threads, BOTH operands PACKED
// (chunk c = kq*128+m, kt block 8192 f16). Used by vt (A=packed paramsT,
// B=packed node; node's BK=32 blocks pair up seamlessly: c*8 spans two).
// ---------------------------------------------------------------------------
__device__ __forceinline__ void gemm_tile_pp(const f16_t* __restrict__ Ap,
                                             const f16_t* __restrict__ Bp,
                                             int kTiles, f16_t* lA, f16_t* lB,
                                             f32x4 acc[4][4])
{
  const int tid  = threadIdx.x;
  const int wave = tid >> 6;
  const int lane = tid & 63;

  const f16_t* pA[4];
  const f16_t* pB[4];
  f16_t* lAb[4];
  f16_t* lBb[4];
#pragma unroll
  for (int i = 0; i < 4; ++i) {
    int c  = i * 256 + tid;
    pA[i]  = Ap + (long)c * 8;                 // packed A (contiguous)
    pB[i]  = Bp + (long)c * 8;                 // packed B (contiguous)
    int cb = i * 256 + wave * 64;
    lAb[i] = lA + (long)cb * 8;
    lBb[i] = lB + (long)cb * 8;
  }
  const int lm = lane & 15;
  const int q  = lane >> 4;
  const int wi = (wave >> 1) * 64;
  const int wj = (wave & 1) * 64;

  for (int kt = 0; kt < kTiles; ++kt) {
    long ko = (long)kt * 8192;
#pragma unroll
    for (int i = 0; i < 4; ++i) GLL16(pA[i] + ko, lAb[i]);
#pragma unroll
    for (int i = 0; i < 4; ++i) GLL16(pB[i] + ko, lBb[i]);
    __syncthreads();
#pragma unroll
    for (int s = 0; s < 2; ++s) {
      f16x8 af[4], bfr[4];
#pragma unroll
      for (int i = 0; i < 4; ++i)
        af[i] = *(const f16x8*)(lA + (((s * 4 + q) * 128) + wi + i * 16 + lm) * 8);
#pragma unroll
      for (int j = 0; j < 4; ++j)
        bfr[j] = *(const f16x8*)(lB + (((s * 4 + q) * 128) + wj + j * 16 + lm) * 8);
#pragma unroll
      for (int i = 0; i < 4; ++i)
#pragma unroll
        for (int j = 0; j < 4; ++j)
          acc[i][j] = __builtin_amdgcn_mfma_f32_16x16x32_f16(af[i], bfr[j], acc[i][j], 0, 0, 0);
    }
    __syncthreads();
  }
}

// ---------------------------------------------------------------------------
// gemm_tile3_p: fused hi/lo 3-product, BK=32, 256 threads, BOTH operands
// packed 128-row panels (kt block 4096 f16). Used by the tw role.
// ---------------------------------------------------------------------------
__device__ __forceinline__ void gemm_tile3_p(const f16_t* __restrict__ Ahp,
                                             const f16_t* __restrict__ Alp,
                                             const f16_t* __restrict__ Bhp,
                                             const f16_t* __restrict__ Blp,
                                             int kTiles,
                                             f16_t* lAh, f16_t* lAl,
                                             f16_t* lBh, f16_t* lBl,
                                             f32x4 acc[4][4])
{
  const int tid  = threadIdx.x;
  const int wave = tid >> 6;
  const int lane = tid & 63;

  const f16_t* pAh[2]; const f16_t* pAl[2];
  const f16_t* pBh[2]; const f16_t* pBl[2];
  f16_t* dAh[2]; f16_t* dAl[2]; f16_t* dBh[2]; f16_t* dBl[2];
#pragma unroll
  for (int i = 0; i < 2; ++i) {
    int c  = i * 256 + tid;        // chunk 0..511 (kq*128+m)
    pAh[i] = Ahp + (long)c * 8;  pAl[i] = Alp + (long)c * 8;
    pBh[i] = Bhp + (long)c * 8;  pBl[i] = Blp + (long)c * 8;
    int cb = i * 256 + wave * 64;
    dAh[i] = lAh + (long)cb * 8;  dAl[i] = lAl + (long)cb * 8;
    dBh[i] = lBh + (long)cb * 8;  dBl[i] = lBl + (long)cb * 8;
  }
  const int lm = lane & 15;
  const int q  = lane >> 4;
  const int wi = (wave >> 1) * 64;
  const int wj = (wave & 1) * 64;

  for (int kt = 0; kt < kTiles; ++kt) {
    long ko = (long)kt * NP_KT;
#pragma unroll
    for (int i = 0; i < 2; ++i) GLL16(pAh[i] + ko, dAh[i]);
#pragma unroll
    for (int i = 0; i < 2; ++i) GLL16(pAl[i] + ko, dAl[i]);
#pragma unroll
    for (int i = 0; i < 2; ++i) GLL16(pBh[i] + ko, dBh[i]);
#pragma unroll
    for (int i = 0; i < 2; ++i) GLL16(pBl[i] + ko, dBl[i]);
    __syncthreads();
    {
      f16x8 ah[4], al[4], bh[4], bl[4];
#pragma unroll
      for (int i = 0; i < 4; ++i)
        ah[i] = *(const f16x8*)(lAh + (q * 128 + wi + i * 16 + lm) * 8);
#pragma unroll
      for (int j = 0; j < 4; ++j)
        bh[j] = *(const f16x8*)(lBh + (q * 128 + wj + j * 16 + lm) * 8);
#pragma unroll
      for (int i = 0; i < 4; ++i)
#pragma unroll
        for (int j = 0; j < 4; ++j)
          acc[i][j] = __builtin_amdgcn_mfma_f32_16x16x32_f16(ah[i], bh[j], acc[i][j], 0, 0, 0);
#pragma unroll
      for (int i = 0; i < 4; ++i)
        al[i] = *(const f16x8*)(lAl + (q * 128 + wi + i * 16 + lm) * 8);
#pragma unroll
      for (int i = 0; i < 4; ++i)
#pragma unroll
        for (int j = 0; j < 4; ++j)
          acc[i][j] = __builtin_amdgcn_mfma_f32_16x16x32_f16(al[i], bh[j], acc[i][j], 0, 0, 0);
#pragma unroll
      for (int j = 0; j < 4; ++j)
        bl[j] = *(const f16x8*)(lBl + (q * 128 + wj + j * 16 + lm) * 8);
#pragma unroll
      for (int i = 0; i < 4; ++i)
#pragma unroll
        for (int j = 0; j < 4; ++j)
          acc[i][j] = __builtin_amdgcn_mfma_f32_16x16x32_f16(ah[i], bl[j], acc[i][j], 0, 0, 0);
    }
    __syncthreads();
  }
}

// ---------------------------------------------------------------------------
// Scores 4-phase mainloop (r4-best skeleton), PACKED operands.
// ---------------------------------------------------------------------------

#define SC8_MFMA_QUAD(i0, j0)                                                   \
  __builtin_amdgcn_s_setprio(1);                                                \
  _Pragma("unroll") for (int ii = 0; ii < 2; ++ii)                              \
  _Pragma("unroll") for (int jj = 0; jj < 2; ++jj) {                            \
    acc[(i0)+ii][(j0)+jj] = __builtin_amdgcn_mfma_f32_16x16x32_f16(             \
        ah[(i0)+ii], bh[(j0)+jj], acc[(i0)+ii][(j0)+jj], 0, 0, 0);              \
    acc[(i0)+ii][(j0)+jj] = __builtin_amdgcn_mfma_f32_16x16x32_f16(             \
        al[(i0)+ii], bh[(j0)+jj], acc[(i0)+ii][(j0)+jj], 0, 0, 0);              \
    acc[(i0)+ii][(j0)+jj] = __builtin_amdgcn_mfma_f32_16x16x32_f16(             \
        ah[(i0)+ii], bl[(j0)+jj], acc[(i0)+ii][(j0)+jj], 0, 0, 0);              \
  }                                                                             \
  __builtin_amdgcn_s_setprio(0);

#define SC8_RD_A(lb, i)                                                \
  ah[i] = *(const f16x8*)((lb) + raA + (i) * 128);                     \
  al[i] = *(const f16x8*)((lb) + 8192 + raA + (i) * 128);
#define SC8_RD_B(lb, j)                                                \
  bh[j] = *(const f16x8*)((lb) + 16384 + rbB + (j) * 128);             \
  bl[j] = *(const f16x8*)((lb) + 20480 + rbB + (j) * 128);

#define SC8_BAR_LGKM                                                   \
  __builtin_amdgcn_s_barrier();                                        \
  asm volatile("s_waitcnt lgkmcnt(0)" ::: "memory");

#define SC8_STAGE_TILE(nb, T)                                    \
  {                                                              \
    long koA = (long)(T) * TP_KT;                                \
    long koB = (long)(T) * NP_KT;                                \
    GLL16(pAh0 + koA, (nb) + dA0);                               \
    GLL16(pAh1 + koA, (nb) + dA1);                               \
    GLL16(pAl0 + koA, (nb) + 8192 + dA0);                        \
    GLL16(pAl1 + koA, (nb) + 8192 + dA1);                        \
    GLL16(pBh + koB, (nb) + 16384 + dB);                         \
    GLL16(pBl + koB, (nb) + 20480 + dB);                         \
  }

#define SC8_TILE(LB, NB, T, ST)                                                 \
  {                                                                             \
    const f16_t* lb = (LB);                                                     \
    f16_t* nb = (NB);                                                           \
    const long koA = (long)((T) + 2) * TP_KT;                                   \
    const long koB = (long)((T) + 2) * NP_KT;                                   \
    f16x8 ah[4], al[4], bh[4], bl[4];                                           \
    SC8_RD_A(lb, 0); SC8_RD_A(lb, 1); SC8_RD_B(lb, 0); SC8_RD_B(lb, 1);         \
    if (ST) { GLL16(pAh0 + koA, nb + dA0); GLL16(pAh1 + koA, nb + dA1); }       \
    SC8_BAR_LGKM;                                                               \
    SC8_MFMA_QUAD(0, 0);                                                        \
    __builtin_amdgcn_s_barrier();                                               \
    SC8_RD_B(lb, 2); SC8_RD_B(lb, 3);                                           \
    if (ST) { GLL16(pAl0 + koA, nb + 8192 + dA0); GLL16(pAl1 + koA, nb + 8192 + dA1); } \
    SC8_BAR_LGKM;                                                               \
    SC8_MFMA_QUAD(0, 2);                                                        \
    __builtin_amdgcn_s_barrier();                                               \
    SC8_RD_A(lb, 2); SC8_RD_A(lb, 3);                                           \
    if (ST) GLL16(pBh + koB, nb + 16384 + dB);                                  \
    SC8_BAR_LGKM;                                                               \
    SC8_MFMA_QUAD(2, 2);                                                        \
    __builtin_amdgcn_s_barrier();                                               \
    if (ST) GLL16(pBl + koB, nb + 20480 + dB);                                  \
    SC8_BAR_LGKM;                                                               \
    SC8_MFMA_QUAD(2, 0);                                                        \
  }

#define SC8_WAIT6_BAR                                                  \
  asm volatile("s_waitcnt vmcnt(6)" ::: "memory");                     \
  __builtin_amdgcn_s_barrier();
#define SC8_WAIT0_BAR                                                  \
  asm volatile("s_waitcnt vmcnt(0)" ::: "memory");                     \
  __builtin_amdgcn_s_barrier();

__device__ __forceinline__ void mainloop8_3p(const f16_t* __restrict__ Ahp,
                                             const f16_t* __restrict__ Alp,
                                             const f16_t* __restrict__ Bhp,
                                             const f16_t* __restrict__ Blp,
                                             f16_t* lds, f32x4 acc[4][4])
{
  f16_t* bu0 = lds;
  f16_t* bu1 = lds + 24576;
  f16_t* bu2 = lds + 49152;

  const int tid  = threadIdx.x;
  const int wave = tid >> 6;
  const int lane = tid & 63;
  const int lm   = lane & 15;
  const int q    = lane >> 4;
  const int wm   = wave >> 1;   // 0..3  (M)
  const int wn   = wave & 1;    // 0..1  (N)

  const f16_t* pAh0 = Ahp + (long)tid * 8;
  const f16_t* pAh1 = Ahp + (long)(tid + 512) * 8;
  const f16_t* pAl0 = Alp + (long)tid * 8;
  const f16_t* pAl1 = Alp + (long)(tid + 512) * 8;
  const f16_t* pBh = Bhp + (long)tid * 8;
  const f16_t* pBl = Blp + (long)tid * 8;
  const int dA0 = wave * 512;
  const int dA1 = 4096 + wave * 512;
  const int dB  = wave * 512;

  const int raA = (q * 256 + wm * 64 + lm) * 8;
  const int rbB = (q * 128 + wn * 64 + lm) * 8;

  SC8_STAGE_TILE(bu0, 0);
  SC8_STAGE_TILE(bu1, 1);
  SC8_WAIT6_BAR;

  for (int it = 0; it < 7; ++it) {
    int t0 = it * 3;
    SC8_TILE(bu0, bu2, t0, 1);     SC8_WAIT6_BAR;
    SC8_TILE(bu1, bu0, t0 + 1, 1); SC8_WAIT6_BAR;
    SC8_TILE(bu2, bu1, t0 + 2, 1); SC8_WAIT6_BAR;
  }
  SC8_TILE(bu0, bu2, 21, 1); SC8_WAIT6_BAR;
  SC8_TILE(bu1, bu0, 22, 0); SC8_WAIT0_BAR;
  SC8_TILE(bu2, bu1, 23, 0);
}

// ---- convert fp32 node -> PACKED f16 hi/lo. grid (24 kt, 64 panels), 256 thr.
__global__ __launch_bounds__(256) void k_cvt_split(const float* __restrict__ src,
                                                   f16_t* __restrict__ hi,
                                                   f16_t* __restrict__ lo)
{
  const int kt    = blockIdx.x;
  const int panel = blockIdx.y;
  const int t     = threadIdx.x;
  long pbase = ((long)panel * 24 + kt) * NP_KT;
#pragma unroll
  for (int i = 0; i < 2; ++i) {
    int c  = i * 256 + t;        // chunk kq*128+m
    int m  = c & 127;
    int kq = c >> 7;
    const float* sp = src + ((long)panel * 128 + m) * 768 + kt * 32 + kq * 8;
    float4 u = *(const float4*)sp;
    float4 w = *(const float4*)(sp + 4);
    f16_t h0 = (f16_t)u.x, h1 = (f16_t)u.y, h2 = (f16_t)u.z, h3 = (f16_t)u.w;
    f16_t h4 = (f16_t)w.x, h5 = (f16_t)w.y, h6 = (f16_t)w.z, h7 = (f16_t)w.w;
    f16x8 hv = {h0, h1, h2, h3, h4, h5, h6, h7};
    f16x8 lv = {(f16_t)(u.x - (float)h0), (f16_t)(u.y - (float)h1),
                (f16_t)(u.z - (float)h2), (f16_t)(u.w - (float)h3),
                (f16_t)(w.x - (float)h4), (f16_t)(w.y - (float)h5),
                (f16_t)(w.z - (float)h6), (f16_t)(w.w - (float)h7)};
    *(f16x8*)(hi + pbase + (long)c * 8) = hv;
    *(f16x8*)(lo + pbase + (long)c * 8) = lv;
  }
}

// ---- merged transposes: z<3 -> W branch z PACKED (hi+lo);
//      z==3 -> paramsT PACKED [vx][br][kt][kq*128+m][8] (NEW r9)
__global__ __launch_bounds__(256) void k_transpose_all(const float* __restrict__ w0,
                                                       const float* __restrict__ w1,
                                                       const float* __restrict__ w2,
                                                       const float* __restrict__ params,
                                                       f16_t* __restrict__ Wh,
                                                       f16_t* __restrict__ Wl,
                                                       f16_t* __restrict__ paramsT)
{
  __shared__ float t[32][33];
  const int z = blockIdx.z;
  const float* src;
  int C;
  if (z < 3) {
    if (blockIdx.y >= 24) return;
    src = (z == 0) ? w0 : ((z == 1) ? w1 : w2);
    C = 768;
  } else {
    src = params;
    C = 768;
  }
  int x = blockIdx.x * 32 + threadIdx.x;
  int y = blockIdx.y * 32 + threadIdx.y;
#pragma unroll
  for (int j = 0; j < 32; j += 8)
    t[threadIdx.y + j][threadIdx.x] = src[(long)(y + j) * C + x];
  __syncthreads();
  int x2 = blockIdx.y * 32 + threadIdx.x;
  int y2 = blockIdx.x * 32 + threadIdx.y;
  if (z < 3) {
    f16_t* hi = Wh + (long)z * WP_Z;
    f16_t* lo = Wl + (long)z * WP_Z;
#pragma unroll
    for (int j = 0; j < 32; j += 8) {
      float v  = t[threadIdx.x][threadIdx.y + j];
      int row = y2 + j;            // 0..767 (transposed row)
      int col = x2;                // 0..767
      f16_t h  = (f16_t)v;
      long off = (long)(row >> 7) * NP_PANEL + (long)(col >> 5) * NP_KT +
                 (long)((col >> 3) & 3) * 1024 + (long)(row & 127) * 8 + (col & 7);
      hi[off] = h;
      lo[off] = (f16_t)(v - (float)h);
    }
  } else {
#pragma unroll
    for (int j = 0; j < 32; j += 8) {
      float v  = t[threadIdx.x][threadIdx.y + j];
      int r  = y2 + j;             // 0..767 (paramsT row)
      int c  = x2;                 // 0..2303 (paramsT col)
      int vx = r >> 7, m = r & 127;
      int br = c / 768;
      int cc = c - br * 768;
      int kt = cc >> 6, kq = (cc >> 3) & 7, e = cc & 7;
      long off = (long)(vx * 3 + br) * PT_VXBR + (long)kt * 8192 +
                 (long)(kq * 128 + m) * 8 + e;
      paramsT[off] = (f16_t)v;
    }
  }
}

// ---- merged tw + vt dispatch. z < g: tw slot z (all packed). z >= g: vt
//      (A=packed paramsT, B=packed node; both contiguous staging now).
__global__ __launch_bounds__(256, 4) void k_tw_vt(const f16_t* __restrict__ nh,
                                                  const f16_t* __restrict__ nl,
                                                  const f16_t* __restrict__ Wh,
                                                  const f16_t* __restrict__ Wl,
                                                  const f16_t* __restrict__ paramsT,
                                                  f16_t* __restrict__ Thi,
                                                  f16_t* __restrict__ Tlo,
                                                  f16_t* __restrict__ Vt,
                                                  int br_base, int g)
{
  __shared__ __align__(16) f16_t lds[16384];   // 32 KB, shared by both roles
  if ((int)blockIdx.z < g) {
    f32x4 acc[4][4];
    ZERO_ACC(acc);
    const int slot = blockIdx.z;
    const long br  = br_base + slot;
    const f16_t* Ahp = nh + (long)blockIdx.x * NP_PANEL;
    const f16_t* Alp = nl + (long)blockIdx.x * NP_PANEL;
    const f16_t* Bhp = Wh + br * WP_Z + (long)blockIdx.y * NP_PANEL;
    const f16_t* Blp = Wl + br * WP_Z + (long)blockIdx.y * NP_PANEL;
    gemm_tile3_p(Ahp, Alp, Bhp, Blp, 24,
                 lds, lds + 4096, lds + 8192, lds + 12288, acc);
    EPI_COORDS;
    long out0 = (long)slot * TP_SLOT;
    long row0 = (long)blockIdx.x * 128;
    long col0 = (long)blockIdx.y * 128;
#pragma unroll
    for (int i = 0; i < 4; ++i)
#pragma unroll
      for (int j = 0; j < 4; ++j)
#pragma unroll
        for (int r = 0; r < 4; ++r) {
          long row = row0 + wi + i * 16 + q * 4 + r;
          long col = col0 + wj + j * 16 + lm;
          float v  = acc[i][j][r];
          f16_t h  = (f16_t)v;
          long off = out0 + (row >> 8) * TP_PANEL + (col >> 5) * TP_KT +
                     ((col >> 3) & 3) * 2048 + (row & 255) * 8 + (col & 7);
          Thi[off] = h;
          Tlo[off] = (f16_t)(v - (float)h);
        }
  } else {
    int id   = blockIdx.x + 64 * (blockIdx.y + 6 * (blockIdx.z - g));  // 0..1151
    int vx   = id % 6;
    int rest = id / 6;
    int vy   = rest & 7;
    int vz   = rest >> 3;        // 0..23
    int b    = vz & 7;
    int br   = vz >> 3;
    f32x4 acc[4][4];
    ZERO_ACC(acc);
    const f16_t* Ap = paramsT + (long)(vx * 3 + br) * PT_VXBR;
    const f16_t* Bp = nh + (long)(b * 8 + vy) * NP_PANEL;
    gemm_tile_pp(Ap, Bp, 12, lds, lds + 8192, acc);
    EPI_COORDS;
    f16_t* C = Vt + ((long)(br * 8 + b) * 768) * 1024;
    long row0 = (long)vx * 128;
    long col0 = (long)vy * 128;
#pragma unroll
    for (int i = 0; i < 4; ++i)
#pragma unroll
      for (int j = 0; j < 4; ++j)
#pragma unroll
        for (int r = 0; r < 4; ++r) {
          long row = row0 + wi + i * 16 + q * 4 + r;
          long col = col0 + wj + j * 16 + lm;
          C[row * 1024 + col] = (f16_t)acc[i][j][r];
        }
  }
}

// ---------------------------------------------------------------------------
// 4-phase scores kernel, packed operands (r8-proven: 144 us).
// ---------------------------------------------------------------------------
__global__ __launch_bounds__(512, 2) void k_gemm_scores8(const f16_t* __restrict__ Thi,
                                                         const f16_t* __restrict__ Tlo,
                                                         const f16_t* __restrict__ nh,
                                                         const f16_t* __restrict__ nl,
                                                         const int* __restrict__ adj0,
                                                         const int* __restrict__ adj1,
                                                         const int* __restrict__ adj2,
                                                         float* __restrict__ S, int br_base)
{
  __shared__ __align__(16) f16_t lds[3 * 24576];   // 144 KB

  const int tid  = threadIdx.x;
  const int wave = tid >> 6;
  const int lane = tid & 63;
  const int lm   = lane & 15;
  const int q    = lane >> 4;
  const int wm   = wave >> 1;
  const int wn   = wave & 1;

  // bijective XCD swizzle over flat block id (nblk % 8 == 0 always)
  const int nblk  = 32 * (int)gridDim.y;
  const int chunk = nblk >> 3;
  int lid = (int)blockIdx.x + 32 * (int)blockIdx.y;
  int swz = (lid & 7) * chunk + (lid >> 3);
  const int zz = swz >> 5;         // (slot*8 + b)
  const int mt = (swz >> 3) & 3;   // M-tile (256 rows)
  const int nt = swz & 7;          // N-tile (128 cols)
  const int b    = zz & 7;
  const int slot = zz >> 3;

  const f16_t* Ahp = Thi + (long)slot * TP_SLOT + (long)(b * 4 + mt) * TP_PANEL;
  const f16_t* Alp = Tlo + (long)slot * TP_SLOT + (long)(b * 4 + mt) * TP_PANEL;
  const f16_t* Bhp = nh + (long)(b * 8 + nt) * NP_PANEL;
  const f16_t* Blp = nl + (long)(b * 8 + nt) * NP_PANEL;

  f32x4 acc[4][4];
  ZERO_ACC(acc);
  mainloop8_3p(Ahp, Alp, Bhp, Blp, lds, acc);

  // epilogue: mask + write fp32 S
  const int br   = br_base + slot;
  const int* adj = (br == 0) ? adj0 : ((br == 1) ? adj1 : adj2);
  const int* adjb = adj + (long)b * 1024 * 1024;
  float* Sb = S + ((long)slot * 8 + b) * 1024 * 1024;
  long row0 = (long)mt * 256 + wm * 64;
  long col0 = (long)nt * 128 + wn * 64;
#pragma unroll
  for (int i = 0; i < 4; ++i)
#pragma unroll
    for (int j = 0; j < 4; ++j)
#pragma unroll
      for (int r = 0; r < 4; ++r) {
        long row = row0 + i * 16 + q * 4 + r;
        long col = col0 + j * 16 + lm;
        float v  = acc[i][j][r];
        v = (adjb[row * 1024 + col] == 1) ? v : -1e7f;
        Sb[row * 1024 + col] = v;
      }
}

// ---- row softmax, WAVE-PER-ROW (4 rows/block, no LDS, no barriers):
//      fp32 S row -> f16 att written IN-PLACE (row stride 2048 f16).
__global__ __launch_bounds__(256) void k_softmax(float* __restrict__ S)
{
  const int wave = threadIdx.x >> 6;
  const int lane = threadIdx.x & 63;
  long row = (long)blockIdx.x * 4 + wave;
  float* rowp = S + row * 1024;
  float4 v[4];
#pragma unroll
  for (int i = 0; i < 4; ++i) v[i] = ((const float4*)rowp)[lane + 64 * i];
  float m = -3e38f;
#pragma unroll
  for (int i = 0; i < 4; ++i)
    m = fmaxf(m, fmaxf(fmaxf(v[i].x, v[i].y), fmaxf(v[i].z, v[i].w)));
#pragma unroll
  for (int off = 32; off; off >>= 1) m = fmaxf(m, __shfl_xor(m, off));
  float e[4][4];
  float s = 0.f;
#pragma unroll
  for (int i = 0; i < 4; ++i) {
    e[i][0] = __expf(v[i].x - m);
    e[i][1] = __expf(v[i].y - m);
    e[i][2] = __expf(v[i].z - m);
    e[i][3] = __expf(v[i].w - m);
    s += e[i][0] + e[i][1] + e[i][2] + e[i][3];
  }
#pragma unroll
  for (int off = 32; off; off >>= 1) s += __shfl_xor(s, off);
  float inv = 1.0f / s;
  f16_t* orow = (f16_t*)rowp;
#pragma unroll
  for (int i = 0; i < 4; ++i) {
    f16x4 o = {(f16_t)(e[i][0] * inv), (f16_t)(e[i][1] * inv),
               (f16_t)(e[i][2] * inv), (f16_t)(e[i][3] * inv)};
    *(f16x4*)(orow + (lane + 64 * i) * 4) = o;
  }
}

// ---------------------------------------------------------------------------
// GEMM-PVF v4: r4 skeleton + rule-#21 both-sides XOR swizzle so staging
// reads full 128B lines from linear att/Vt:
//  - stage chunk c (row=c>>3, cg=c&7): global reads colgroup cg^(row&7)
//    -> each wave reads 8 rows x 128B fully-covered lines (was 64 partials).
//  - LDS stays linear; ds_read uses the same XOR: row*64 + (k^(row&7))*8.
//  Bank check: 8 lanes per 128B row-region per ds_read_b128 = LDS line
//  throughput, conflict-free. MFMA inputs bit-identical to v2.
// ---------------------------------------------------------------------------
__global__ __launch_bounds__(256, 2) void k_gemm_pvf(const float* __restrict__ S,
                                                     const f16_t* __restrict__ Vt,
                                                     float* __restrict__ out,
                                                     int g, int br_base)
{
  __shared__ __align__(16) f16_t lds[3 * 12288];   // 72 KB (per buf: A 8192, B 4096 f16)
  const int tid  = threadIdx.x;
  const int wave = tid >> 6;
  const int lane = tid & 63;
  const int lm   = lane & 15;
  const int q    = lane >> 4;
  const int wi   = (wave >> 1) * 64;
  const int wj   = (wave & 1) * 32;
  const int b    = blockIdx.z;
  const int TT   = 16 * g;

  // swizzled staging offsets: chunk c -> row = c>>3, colgroup (c&7)^(row&7)
  long aoff[4];
  int  adst[4];
#pragma unroll
  for (int i = 0; i < 4; ++i) {
    int c   = i * 256 + tid;       // 1024 chunks (A: 128 rows x 8 cgs)
    int rw  = c >> 3;
    int cg  = (c & 7) ^ (rw & 7);
    aoff[i] = (long)rw * 2048 + cg * 8;
    adst[i] = (i * 256 + wave * 64) * 8;
  }
  long boff[2];
  int  bdst[2];
#pragma unroll
  for (int i = 0; i < 2; ++i) {
    int c   = i * 256 + tid;       // 512 chunks (B: 64 rows x 8 cgs)
    int rw  = c >> 3;
    int cg  = (c & 7) ^ (rw & 7);
    boff[i] = (long)rw * 1024 + cg * 8;
    bdst[i] = 8192 + (i * 256 + wave * 64) * 8;
  }
  const long abase = ((long)b * 1024 + (long)blockIdx.x * 128) * 2048;
  const long bcol  = (long)blockIdx.y * 64 * 1024;

  f32x4 acc[4][2];
#pragma unroll
  for (int i = 0; i < 4; ++i)
#pragma unroll
    for (int j = 0; j < 2; ++j)
      acc[i][j] = (f32x4){0.f, 0.f, 0.f, 0.f};

#define PVF_STAGE(TG, BUF)                                                     \
  {                                                                            \
    int slot_ = (TG) >> 4;                                                     \
    long ko_  = (long)((TG) & 15) * 64;                                        \
    const f16_t* As_ = (const f16_t*)(S + (long)slot_ * 8 * 1024 * 1024) + abase; \
    const f16_t* Bs_ = Vt + (((long)(br_base + slot_) * 8 + b) * 768) * 1024 + bcol; \
    f16_t* L_ = lds + (BUF) * 12288;                                           \
    GLL16(As_ + aoff[0] + ko_, L_ + adst[0]);                                  \
    GLL16(As_ + aoff[1] + ko_, L_ + adst[1]);                                  \
    GLL16(As_ + aoff[2] + ko_, L_ + adst[2]);                                  \
    GLL16(As_ + aoff[3] + ko_, L_ + adst[3]);                                  \
    GLL16(Bs_ + boff[0] + ko_, L_ + bdst[0]);                                  \
    GLL16(Bs_ + boff[1] + ko_, L_ + bdst[1]);                                  \
  }

#define PVF_COMPUTE(BUF)                                                       \
  {                                                                            \
    const f16_t* L_ = lds + (BUF) * 12288;                                     \
    _Pragma("unroll") for (int s2 = 0; s2 < 2; ++s2) {                         \
      const int kx = (s2 * 4 + q) ^ (lm & 7);                                  \
      f16x8 af[4], bfr[2];                                                     \
      _Pragma("unroll") for (int i = 0; i < 4; ++i)                            \
        af[i] = *(const f16x8*)(L_ + (wi + i * 16 + lm) * 64 + kx * 8);        \
      _Pragma("unroll") for (int j = 0; j < 2; ++j)                            \
        bfr[j] = *(const f16x8*)(L_ + 8192 + (wj + j * 16 + lm) * 64 + kx * 8); \
      _Pragma("unroll") for (int i = 0; i < 4; ++i)                            \
        _Pragma("unroll") for (int j = 0; j < 2; ++j)                          \
          acc[i][j] = __builtin_amdgcn_mfma_f32_16x16x32_f16(af[i], bfr[j], acc[i][j], 0, 0, 0); \
    }                                                                          \
  }

  PVF_STAGE(0, 0);
  PVF_STAGE(1, 1);
  asm volatile("s_waitcnt vmcnt(6)" ::: "memory");
  __builtin_amdgcn_s_barrier();

  int buf = 0;
  for (int tg = 0; tg < TT; ++tg) {
    int nb = buf + 2; if (nb >= 3) nb -= 3;
    if (tg + 2 < TT) PVF_STAGE(tg + 2, nb);
    PVF_COMPUTE(buf);
    if (tg + 2 < TT) {
      asm volatile("s_waitcnt vmcnt(6)" ::: "memory");
    } else if (tg + 1 < TT) {
      asm volatile("s_waitcnt vmcnt(0)" ::: "memory");
    }
    __builtin_amdgcn_s_barrier();
    ++buf; if (buf == 3) buf = 0;
  }
#undef PVF_STAGE
#undef PVF_COMPUTE

  float* Cb = out + (long)b * 1024 * 768;
  long row0 = (long)blockIdx.x * 128;
  long col0 = (long)blockIdx.y * 64;
#pragma unroll
  for (int i = 0; i < 4; ++i)
#pragma unroll
    for (int j = 0; j < 2; ++j)
#pragma unroll
      for (int r = 0; r < 4; ++r) {
        long row = row0 + wi + i * 16 + q * 4 + r;
        long col = col0 + wj + j * 16 + lm;
        float v  = acc[i][j][r];
        if (br_base != 0) v += Cb[row * 768 + col];
        Cb[row * 768 + col] = v;
      }
}

extern "C" void kernel_launch(void* const* d_in, const int* in_sizes, int n_in,
                              void* d_out, int out_size, void* d_ws, size_t ws_size,
                              hipStream_t stream)
{
  const float* node    = (const float*)d_in[0];
  const int*   adjp[3] = {(const int*)d_in[1], (const int*)d_in[2], (const int*)d_in[3]};
  const float* Wp[3]   = {(const float*)d_in[4], (const float*)d_in[5], (const float*)d_in[6]};
  const float* params  = (const float*)d_in[7];
  float* out = (float*)d_out;

  const size_t SZ_W3 = 3ull * 768 * 768 * 2;     // f16 [3] packed W
  const size_t SZ_PT = 768ull * 2304 * 2;        // f16 packed paramsT
  const size_t SZ_N  = 8192ull * 768 * 2;        // f16 packed node
  const size_t SZ_VT = 24ull * 768 * 1024 * 2;   // f16 [3][8][768][1024] linear
  const size_t SZ_T  = 8192ull * 768 * 2;        // f16 per slot packed T
  const size_t SZ_S  = 8ull * 1024 * 1024 * 4;   // fp32 per slot
  const size_t FIXED = 2 * SZ_W3 + SZ_PT + 2 * SZ_N + SZ_VT;
  const size_t SLOT  = 2 * SZ_T + SZ_S;

  int NBR = 1;
  if (ws_size >= FIXED + 3 * SLOT) NBR = 3;
  else if (ws_size >= FIXED + 2 * SLOT) NBR = 2;
  else if (ws_size < FIXED + SLOT) return;  // can't run

  char* base = (char*)d_ws;
  size_t off = 0;
  f16_t* Wh      = (f16_t*)(base + off); off += SZ_W3;
  f16_t* Wl      = (f16_t*)(base + off); off += SZ_W3;
  f16_t* paramsT = (f16_t*)(base + off); off += SZ_PT;
  f16_t* node_hi = (f16_t*)(base + off); off += SZ_N;
  f16_t* node_lo = (f16_t*)(base + off); off += SZ_N;
  f16_t* Vt      = (f16_t*)(base + off); off += SZ_VT;
  f16_t* Thi     = (f16_t*)(base + off); off += (size_t)NBR * SZ_T;
  f16_t* Tlo     = (f16_t*)(base + off); off += (size_t)NBR * SZ_T;
  float* S       = (float*)(base + off); off += (size_t)NBR * SZ_S;

  k_cvt_split<<<dim3(24, 64, 1), 256, 0, stream>>>(node, node_hi, node_lo);
  k_transpose_all<<<dim3(24, 72, 4), dim3(32, 8), 0, stream>>>(Wp[0], Wp[1], Wp[2], params,
                                                               Wh, Wl, paramsT);

  int done = 0;
  while (done < 3) {
    int g = (3 - done < NBR) ? (3 - done) : NBR;
    int vtz = (done == 0) ? 3 : 0;
    k_tw_vt<<<dim3(64, 6, g + vtz), 256, 0, stream>>>(node_hi, node_lo, Wh, Wl, paramsT,
                                                      Thi, Tlo, Vt, done, g);
    k_gemm_scores8<<<dim3(32, 8 * g, 1), 512, 0, stream>>>(Thi, Tlo, node_hi, node_lo,
                                                           adjp[0], adjp[1], adjp[2], S, done);
    k_softmax<<<2048 * g, 256, 0, stream>>>(S);
    k_gemm_pvf<<<dim3(8, 12, 8), 256, 0, stream>>>(S, Vt, out, g, done);
    done += g;
  }
}